// Round 2
// baseline (234.179 us; speedup 1.0000x reference)
//
#include <hip/hip_runtime.h>

#define N_TOK 2048
#define DMODEL 1024
#define NH 16
#define DK 64

typedef __attribute__((ext_vector_type(8))) short bfrag;   // 8 bf16 = one MFMA A/B operand
typedef __attribute__((ext_vector_type(4))) float f32x4;   // MFMA C/D

__device__ __forceinline__ unsigned short f2bf(float f) {
    unsigned u = __builtin_bit_cast(unsigned, f);
    u += 0x7FFFu + ((u >> 16) & 1u);          // round-to-nearest-even
    return (unsigned short)(u >> 16);
}
__device__ __forceinline__ float bf2f(unsigned short u) {
    unsigned x = ((unsigned)u) << 16;
    return __builtin_bit_cast(float, x);
}
// pack 4 consecutive values into hi/lo uint2 (4 bf16 each)
__device__ __forceinline__ void pack4(float a, float b, float c, float d, uint2& ph, uint2& pl) {
    unsigned short ah = f2bf(a), bh = f2bf(b), ch = f2bf(c), dh = f2bf(d);
    unsigned short al = f2bf(a - bf2f(ah)), bl = f2bf(b - bf2f(bh));
    unsigned short cl = f2bf(c - bf2f(ch)), dl = f2bf(d - bf2f(dh));
    ph = make_uint2((unsigned)ah | ((unsigned)bh << 16), (unsigned)ch | ((unsigned)dh << 16));
    pl = make_uint2((unsigned)al | ((unsigned)bl << 16), (unsigned)cl | ((unsigned)dl << 16));
}
__device__ __forceinline__ void split8(const float* f, bfrag& h_, bfrag& l_) {
    #pragma unroll
    for (int i = 0; i < 8; ++i) {
        unsigned short hb = f2bf(f[i]);
        h_[i] = (short)hb;
        l_[i] = (short)f2bf(f[i] - bf2f(hb));
    }
}

// swizzled byte offset inside a [rows][64 bf16] LDS tile (128 B rows).
__device__ __forceinline__ int swz(int row, int b) {
    return row * 128 + (b ^ ((row & 7) << 4));
}

// ---------------------------------------------------------------------------
// Kernel 1: per-head input projections, split-bf16 (hi+lo) for ~f32 accuracy.
// out[h][n][k] = in[n][:] @ W[h][:,k] + b[h][k]
// GEMM tile 128x128 (2 heads), BK=64, 4 waves (2x2), each wave 64x64.
// Q,K results -> f32 workspace; V -> bf16.
// ---------------------------------------------------------------------------
__global__ __launch_bounds__(256) void proj_kernel(
    const float* __restrict__ Qin, const float* __restrict__ Kin, const float* __restrict__ Vin,
    const float* __restrict__ Wq_, const float* __restrict__ bq_,
    const float* __restrict__ Wk_, const float* __restrict__ bk_,
    const float* __restrict__ Wv_, const float* __restrict__ bv_,
    float* __restrict__ Qf, float* __restrict__ Kf, unsigned short* __restrict__ Vh)
{
    const float* A; const float* W; const float* bias;
    if (blockIdx.z == 0)      { A = Qin; W = Wq_; bias = bq_; }
    else if (blockIdx.z == 1) { A = Kin; W = Wk_; bias = bk_; }
    else                      { A = Vin; W = Wv_; bias = bv_; }

    __shared__ alignas(16) unsigned char sAh[16384];   // [128 rows][64 bf16] swizzled, hi
    __shared__ alignas(16) unsigned char sAl[16384];   // lo
    __shared__ alignas(16) unsigned char sBh[16384];   // [128 j][64 d] swizzled (B^T), hi
    __shared__ alignas(16) unsigned char sBl[16384];   // lo

    const int tid = threadIdx.x;
    const int lane = tid & 63;
    const int w = tid >> 6;               // 0..3
    const int wm = w >> 1, wn = w & 1;    // 2x2 wave grid
    const int g = lane >> 4, li = lane & 15;

    const int row0 = blockIdx.x * 128;    // token rows
    const int col0 = blockIdx.y * 128;    // output cols (h*64+k)

    f32x4 acc[4][4];
    #pragma unroll
    for (int m = 0; m < 4; ++m)
        #pragma unroll
        for (int n = 0; n < 4; ++n) acc[m][n] = f32x4{0.f, 0.f, 0.f, 0.f};

    for (int kt = 0; kt < DMODEL; kt += 64) {
        __syncthreads();
        // stage A tile: 128x64 f32 -> hi/lo bf16, swizzled
        #pragma unroll
        for (int p = 0; p < 8; ++p) {
            int idx = (p * 256 + tid) * 4;
            int r = idx >> 6, c = idx & 63;
            const float4 v = *reinterpret_cast<const float4*>(A + (size_t)(row0 + r) * DMODEL + kt + c);
            uint2 ph, pl;
            pack4(v.x, v.y, v.z, v.w, ph, pl);
            *reinterpret_cast<uint2*>(sAh + swz(r, c * 2)) = ph;
            *reinterpret_cast<uint2*>(sAl + swz(r, c * 2)) = pl;
        }
        // stage B^T tile: W[h][d][k] -> sB[j][d], 4x4 register transpose, hi/lo
        #pragma unroll
        for (int p = 0; p < 2; ++p) {
            int c = p * 256 + tid;          // 0..511
            int dq = c & 15;                // d-quad (d = dq*4..+3)
            int j4 = c >> 4;                // j-quad (j = j4*4..+3), 0..31
            int j = j4 * 4;
            int hh  = (col0 + j) >> 6;
            int kkk = (col0 + j) & 63;
            const float* src = W + ((size_t)hh * DMODEL + kt + dq * 4) * DK + kkk;
            float4 r0 = *reinterpret_cast<const float4*>(src);
            float4 r1 = *reinterpret_cast<const float4*>(src + DK);
            float4 r2 = *reinterpret_cast<const float4*>(src + 2 * DK);
            float4 r3 = *reinterpret_cast<const float4*>(src + 3 * DK);
            uint2 ph, pl;
            pack4(r0.x, r1.x, r2.x, r3.x, ph, pl);
            *reinterpret_cast<uint2*>(sBh + swz(j + 0, dq * 8)) = ph;
            *reinterpret_cast<uint2*>(sBl + swz(j + 0, dq * 8)) = pl;
            pack4(r0.y, r1.y, r2.y, r3.y, ph, pl);
            *reinterpret_cast<uint2*>(sBh + swz(j + 1, dq * 8)) = ph;
            *reinterpret_cast<uint2*>(sBl + swz(j + 1, dq * 8)) = pl;
            pack4(r0.z, r1.z, r2.z, r3.z, ph, pl);
            *reinterpret_cast<uint2*>(sBh + swz(j + 2, dq * 8)) = ph;
            *reinterpret_cast<uint2*>(sBl + swz(j + 2, dq * 8)) = pl;
            pack4(r0.w, r1.w, r2.w, r3.w, ph, pl);
            *reinterpret_cast<uint2*>(sBh + swz(j + 3, dq * 8)) = ph;
            *reinterpret_cast<uint2*>(sBl + swz(j + 3, dq * 8)) = pl;
        }
        __syncthreads();

        #pragma unroll
        for (int kk = 0; kk < 2; ++kk) {
            bfrag afh[4], afl[4], bfh[4], bfl[4];
            #pragma unroll
            for (int m = 0; m < 4; ++m) {
                afh[m] = *reinterpret_cast<const bfrag*>(sAh + swz(wm * 64 + m * 16 + li, kk * 64 + g * 16));
                afl[m] = *reinterpret_cast<const bfrag*>(sAl + swz(wm * 64 + m * 16 + li, kk * 64 + g * 16));
            }
            #pragma unroll
            for (int n = 0; n < 4; ++n) {
                bfh[n] = *reinterpret_cast<const bfrag*>(sBh + swz(wn * 64 + n * 16 + li, kk * 64 + g * 16));
                bfl[n] = *reinterpret_cast<const bfrag*>(sBl + swz(wn * 64 + n * 16 + li, kk * 64 + g * 16));
            }
            #pragma unroll
            for (int m = 0; m < 4; ++m)
                #pragma unroll
                for (int n = 0; n < 4; ++n) {
                    acc[m][n] = __builtin_amdgcn_mfma_f32_16x16x32_bf16(afh[m], bfh[n], acc[m][n], 0, 0, 0);
                    acc[m][n] = __builtin_amdgcn_mfma_f32_16x16x32_bf16(afl[m], bfh[n], acc[m][n], 0, 0, 0);
                    acc[m][n] = __builtin_amdgcn_mfma_f32_16x16x32_bf16(afh[m], bfl[n], acc[m][n], 0, 0, 0);
                }
        }
    }

    // epilogue: +bias; Q,K -> f32 head-major [h][n][k]; V -> bf16
    #pragma unroll
    for (int m = 0; m < 4; ++m) {
        #pragma unroll
        for (int n = 0; n < 4; ++n) {
            int colg = col0 + wn * 64 + n * 16 + li;
            float bb = bias[colg];                      // bias is flat (H*DK)
            int hh = colg >> 6, k = colg & 63;
            #pragma unroll
            for (int r = 0; r < 4; ++r) {
                int rowg = row0 + wm * 64 + m * 16 + g * 4 + r;
                size_t o = ((size_t)hh * N_TOK + rowg) * DK + k;
                float val = acc[m][n][r] + bb;
                if (blockIdx.z == 0)      Qf[o] = val;
                else if (blockIdx.z == 1) Kf[o] = val;
                else                      Vh[o] = f2bf(val);
            }
        }
    }
}

// ---------------------------------------------------------------------------
// Kernel 2: flash attention per (q-tile, head). 8 waves x 16 q-rows, KV tile 64.
// Q,K in f32, split hi/lo -> 3-MFMA QK^T for ~f32 score accuracy.
// softmax scale d_k^-0.5 applied post-softmax (== scale final O by 0.125/l).
// ---------------------------------------------------------------------------
__global__ __launch_bounds__(512) void attn_kernel(
    const float* __restrict__ Qf,
    const float* __restrict__ Kf,
    const unsigned short* __restrict__ Vh,
    unsigned short* __restrict__ Hc)
{
    __shared__ alignas(16) unsigned char sKh[8192];   // [64 key][64 k] swizzled, hi
    __shared__ alignas(16) unsigned char sKl[8192];   // lo
    __shared__ alignas(16) unsigned char sV[8192];    // [64 v ][64 key] swizzled (V^T)
    __shared__ alignas(16) unsigned char sP[16384];   // per-wave 16x64 P tiles

    const int tid = threadIdx.x;
    const int lane = tid & 63;
    const int w = tid >> 6;               // 0..7
    const int g = lane >> 4, li = lane & 15;
    const int h = blockIdx.y;
    const int qrow0 = blockIdx.x * 128 + w * 16;

    const float* Qbase = Qf + (size_t)h * N_TOK * DK;
    const float* Kbase = Kf + (size_t)h * N_TOK * DK;
    const unsigned short* Vbase = Vh + (size_t)h * N_TOK * DK;
    unsigned char* sPw = sP + w * 2048;

    // Q fragments (hi/lo) held in registers for the whole kernel
    bfrag aqh[2], aql[2];
    #pragma unroll
    for (int kk = 0; kk < 2; ++kk) {
        float qtmp[8];
        const float* qp = Qbase + (size_t)(qrow0 + li) * DK + kk * 32 + g * 8;
        *reinterpret_cast<float4*>(qtmp)     = *reinterpret_cast<const float4*>(qp);
        *reinterpret_cast<float4*>(qtmp + 4) = *reinterpret_cast<const float4*>(qp + 4);
        split8(qtmp, aqh[kk], aql[kk]);
    }

    f32x4 accO[4];
    #pragma unroll
    for (int n = 0; n < 4; ++n) accO[n] = f32x4{0.f, 0.f, 0.f, 0.f};
    float mrun[4], lrun[4];
    #pragma unroll
    for (int r = 0; r < 4; ++r) { mrun[r] = -3.0e38f; lrun[r] = 0.f; }

    for (int t = 0; t < N_TOK; t += 64) {
        __syncthreads();
        {   // stage K tile f32 -> hi/lo bf16, swizzled (512 threads, 8 floats each)
            int r = tid >> 3;
            int cq = tid & 7;
            const float* src = Kbase + (size_t)(t + r) * DK + cq * 8;
            float4 x = *reinterpret_cast<const float4*>(src);
            float4 y = *reinterpret_cast<const float4*>(src + 4);
            uint2 h0, l0, h1, l1;
            pack4(x.x, x.y, x.z, x.w, h0, l0);
            pack4(y.x, y.y, y.z, y.w, h1, l1);
            *reinterpret_cast<uint4*>(sKh + swz(r, cq * 16)) = make_uint4(h0.x, h0.y, h1.x, h1.y);
            *reinterpret_cast<uint4*>(sKl + swz(r, cq * 16)) = make_uint4(l0.x, l0.y, l1.x, l1.y);
        }
        {   // stage V^T: lane<->row mapping keeps the 2B scatter conflict-free
            int mr = tid & 63;
            int v0 = (tid >> 6) * 8;
            bfrag vv = *reinterpret_cast<const bfrag*>(Vbase + (size_t)(t + mr) * DK + v0);
            #pragma unroll
            for (int e = 0; e < 8; ++e)
                *reinterpret_cast<unsigned short*>(sV + swz(v0 + e, mr * 2)) = (unsigned short)vv[e];
        }
        __syncthreads();

        // S = Q K^T  (16 q-rows x 64 keys per wave), split-bf16 3-MFMA
        f32x4 s[4];
        #pragma unroll
        for (int n = 0; n < 4; ++n) s[n] = f32x4{0.f, 0.f, 0.f, 0.f};
        #pragma unroll
        for (int kk = 0; kk < 2; ++kk) {
            #pragma unroll
            for (int n = 0; n < 4; ++n) {
                bfrag bkh = *reinterpret_cast<const bfrag*>(sKh + swz(n * 16 + li, kk * 64 + g * 16));
                bfrag bkl = *reinterpret_cast<const bfrag*>(sKl + swz(n * 16 + li, kk * 64 + g * 16));
                s[n] = __builtin_amdgcn_mfma_f32_16x16x32_bf16(aqh[kk], bkh, s[n], 0, 0, 0);
                s[n] = __builtin_amdgcn_mfma_f32_16x16x32_bf16(aql[kk], bkh, s[n], 0, 0, 0);
                s[n] = __builtin_amdgcn_mfma_f32_16x16x32_bf16(aqh[kk], bkl, s[n], 0, 0, 0);
            }
        }

        // online softmax; row r of this lane = qrow0 + g*4 + r, cols across 16 lanes
        float tmax[4];
        #pragma unroll
        for (int r = 0; r < 4; ++r)
            tmax[r] = fmaxf(fmaxf(s[0][r], s[1][r]), fmaxf(s[2][r], s[3][r]));
        #pragma unroll
        for (int off = 1; off < 16; off <<= 1)
            #pragma unroll
            for (int r = 0; r < 4; ++r)
                tmax[r] = fmaxf(tmax[r], __shfl_xor(tmax[r], off));
        float sc[4];
        #pragma unroll
        for (int r = 0; r < 4; ++r) {
            float nm = fmaxf(mrun[r], tmax[r]);
            sc[r] = __expf(mrun[r] - nm);
            mrun[r] = nm;
            lrun[r] *= sc[r];
        }
        #pragma unroll
        for (int n = 0; n < 4; ++n)
            #pragma unroll
            for (int r = 0; r < 4; ++r)
                accO[n][r] *= sc[r];

        float psum[4] = {0.f, 0.f, 0.f, 0.f};
        #pragma unroll
        for (int n = 0; n < 4; ++n) {
            #pragma unroll
            for (int r = 0; r < 4; ++r) {
                float p = __expf(s[n][r] - mrun[r]);
                unsigned short pb = f2bf(p);
                psum[r] += bf2f(pb);       // sum the SAME rounded values PV uses
                *reinterpret_cast<unsigned short*>(sPw + swz(g * 4 + r, (n * 16 + li) * 2)) = pb;
            }
        }
        #pragma unroll
        for (int off = 1; off < 16; off <<= 1)
            #pragma unroll
            for (int r = 0; r < 4; ++r)
                psum[r] += __shfl_xor(psum[r], off);
        #pragma unroll
        for (int r = 0; r < 4; ++r) lrun[r] += psum[r];

        // O += P @ V_tile  (P re-read from LDS in A-fragment layout)
        #pragma unroll
        for (int kk = 0; kk < 2; ++kk) {
            bfrag pa = *reinterpret_cast<const bfrag*>(sPw + swz(li, kk * 64 + g * 16));
            #pragma unroll
            for (int n = 0; n < 4; ++n) {
                bfrag vb = *reinterpret_cast<const bfrag*>(sV + swz(n * 16 + li, kk * 64 + g * 16));
                accO[n] = __builtin_amdgcn_mfma_f32_16x16x32_bf16(pa, vb, accO[n], 0, 0, 0);
            }
        }
    }

    // epilogue: O * (d_k^-0.5 / l) -> concat buffer [n][h*64+v] (bf16)
    #pragma unroll
    for (int r = 0; r < 4; ++r) {
        float inv = 0.125f / lrun[r];
        int rowg = qrow0 + g * 4 + r;
        #pragma unroll
        for (int n = 0; n < 4; ++n) {
            int colg = h * 64 + n * 16 + li;
            Hc[(size_t)rowg * (NH * DK) + colg] = f2bf(accO[n][r] * inv);
        }
    }
}

// ---------------------------------------------------------------------------
// Kernel 3: output projection. out = Hc(bf16 2048x1024) @ Wo(f32 1024x1024) + bo
// tile 128x64, BK=64, 4 waves (each 32 rows x 64 cols).
// ---------------------------------------------------------------------------
__global__ __launch_bounds__(256) void oproj_kernel(
    const unsigned short* __restrict__ Hc,
    const float* __restrict__ Wo,
    const float* __restrict__ bo,
    float* __restrict__ out)
{
    __shared__ alignas(16) unsigned char sA[16384];   // [128][64] bf16 swizzled
    __shared__ alignas(16) unsigned char sB[8192];    // [64 j][64 d] swizzled (Wo^T)

    const int tid = threadIdx.x;
    const int lane = tid & 63;
    const int w = tid >> 6;               // 0..3, rows w*32..+32
    const int g = lane >> 4, li = lane & 15;
    const int row0 = blockIdx.x * 128;
    const int col0 = blockIdx.y * 64;

    f32x4 acc[2][4];
    #pragma unroll
    for (int m = 0; m < 2; ++m)
        #pragma unroll
        for (int n = 0; n < 4; ++n) acc[m][n] = f32x4{0.f, 0.f, 0.f, 0.f};

    for (int kt = 0; kt < DMODEL; kt += 64) {
        __syncthreads();
        // stage A (already bf16): linear 16B chunks
        #pragma unroll
        for (int p = 0; p < 4; ++p) {
            int c = p * 256 + tid;            // 0..1023
            int r = c >> 3, off = (c & 7) * 16;
            *reinterpret_cast<uint4*>(sA + swz(r, off)) =
                *reinterpret_cast<const uint4*>(Hc + (size_t)(row0 + r) * DMODEL + kt + (c & 7) * 8);
        }
        // stage Wo^T tile: Wo[d][j] -> sB[j][d], 4x4 register transpose
        {
            int dq = tid & 15;                // d = dq*4..+3
            int j4 = tid >> 4;                // j = j4*4..+3, 0..15
            int j = j4 * 4;
            const float* src = Wo + (size_t)(kt + dq * 4) * DMODEL + col0 + j;
            float4 r0 = *reinterpret_cast<const float4*>(src);
            float4 r1 = *reinterpret_cast<const float4*>(src + DMODEL);
            float4 r2 = *reinterpret_cast<const float4*>(src + 2 * DMODEL);
            float4 r3 = *reinterpret_cast<const float4*>(src + 3 * DMODEL);
            uint2 ph, pl;
            pack4(r0.x, r1.x, r2.x, r3.x, ph, pl);
            *reinterpret_cast<uint2*>(sB + swz(j + 0, dq * 8)) = ph;
            pack4(r0.y, r1.y, r2.y, r3.y, ph, pl);
            *reinterpret_cast<uint2*>(sB + swz(j + 1, dq * 8)) = ph;
            pack4(r0.z, r1.z, r2.z, r3.z, ph, pl);
            *reinterpret_cast<uint2*>(sB + swz(j + 2, dq * 8)) = ph;
            pack4(r0.w, r1.w, r2.w, r3.w, ph, pl);
            *reinterpret_cast<uint2*>(sB + swz(j + 3, dq * 8)) = ph;
        }
        __syncthreads();

        #pragma unroll
        for (int kk = 0; kk < 2; ++kk) {
            bfrag af[2], bf_[4];
            #pragma unroll
            for (int m = 0; m < 2; ++m)
                af[m] = *reinterpret_cast<const bfrag*>(sA + swz(w * 32 + m * 16 + li, kk * 64 + g * 16));
            #pragma unroll
            for (int n = 0; n < 4; ++n)
                bf_[n] = *reinterpret_cast<const bfrag*>(sB + swz(n * 16 + li, kk * 64 + g * 16));
            #pragma unroll
            for (int m = 0; m < 2; ++m)
                #pragma unroll
                for (int n = 0; n < 4; ++n)
                    acc[m][n] = __builtin_amdgcn_mfma_f32_16x16x32_bf16(af[m], bf_[n], acc[m][n], 0, 0, 0);
        }
    }

    #pragma unroll
    for (int m = 0; m < 2; ++m) {
        #pragma unroll
        for (int n = 0; n < 4; ++n) {
            int colg = col0 + n * 16 + li;
            float bb = bo[colg];
            #pragma unroll
            for (int r = 0; r < 4; ++r) {
                int rowg = row0 + w * 32 + m * 16 + g * 4 + r;
                out[(size_t)rowg * DMODEL + colg] = acc[m][n][r] + bb;
            }
        }
    }
}

extern "C" void kernel_launch(void* const* d_in, const int* in_sizes, int n_in,
                              void* d_out, int out_size, void* d_ws, size_t ws_size,
                              hipStream_t stream) {
    (void)in_sizes; (void)n_in; (void)out_size; (void)ws_size;
    const float* Q  = (const float*)d_in[0];
    const float* K  = (const float*)d_in[1];
    const float* V  = (const float*)d_in[2];
    // d_in[3] = mask (unused by reference forward)
    const float* Wq = (const float*)d_in[4];
    const float* bq = (const float*)d_in[5];
    const float* Wk = (const float*)d_in[6];
    const float* bk = (const float*)d_in[7];
    const float* Wv = (const float*)d_in[8];
    const float* bv = (const float*)d_in[9];
    const float* Wo = (const float*)d_in[10];
    const float* bo = (const float*)d_in[11];
    float* out = (float*)d_out;

    const size_t HSZ = (size_t)NH * N_TOK * DK;        // 2M elems per head-major buffer
    float* Qf = (float*)d_ws;                          // 8 MiB
    float* Kf = Qf + HSZ;                              // 8 MiB
    unsigned short* Vh = (unsigned short*)(Kf + HSZ);  // 4 MiB
    unsigned short* Hc = Vh + HSZ;                     // 4 MiB  [N][H*DK] concat

    proj_kernel<<<dim3(16, 8, 3), 256, 0, stream>>>(Q, K, V, Wq, bq, Wk, bk, Wv, bv, Qf, Kf, Vh);
    attn_kernel<<<dim3(16, 16), 512, 0, stream>>>(Qf, Kf, Vh, Hc);
    oproj_kernel<<<dim3(16, 16), 256, 0, stream>>>(Hc, Wo, bo, out);
}

// Round 3
// 197.254 us; speedup vs baseline: 1.1872x; 1.1872x over previous
//
#include <hip/hip_runtime.h>

#define N_TOK 2048
#define DMODEL 1024
#define NH 16
#define DK 64

typedef __attribute__((ext_vector_type(8))) short bfrag;   // 8 bf16 = one MFMA A/B operand
typedef __attribute__((ext_vector_type(4))) float f32x4;   // MFMA C/D

__device__ __forceinline__ unsigned short f2bf(float f) {
    unsigned u = __builtin_bit_cast(unsigned, f);
    u += 0x7FFFu + ((u >> 16) & 1u);          // round-to-nearest-even
    return (unsigned short)(u >> 16);
}
__device__ __forceinline__ float bf2f(unsigned short u) {
    unsigned x = ((unsigned)u) << 16;
    return __builtin_bit_cast(float, x);
}

// swizzled byte offset inside a [rows][64 bf16] LDS tile (128 B rows).
__device__ __forceinline__ int swz(int row, int b) {
    return row * 128 + (b ^ ((row & 7) << 4));
}

// ---------------------------------------------------------------------------
// Prep 1: split activations Q,K,V (f32 row-major [2048][1024]) into bf16
// hi (all) and lo (Q,K only) row-major arrays.
// ---------------------------------------------------------------------------
__global__ __launch_bounds__(256) void split_act(
    const float* __restrict__ Qin, const float* __restrict__ Kin, const float* __restrict__ Vin,
    unsigned short* __restrict__ Ah0, unsigned short* __restrict__ Ah1, unsigned short* __restrict__ Ah2,
    unsigned short* __restrict__ Al0, unsigned short* __restrict__ Al1)
{
    const int z = blockIdx.y;
    const float* src = (z == 0) ? Qin : (z == 1) ? Kin : Vin;
    unsigned short* dh = (z == 0) ? Ah0 : (z == 1) ? Ah1 : Ah2;
    unsigned short* dl = (z == 0) ? Al0 : (z == 1) ? Al1 : nullptr;

    size_t base = ((size_t)blockIdx.x * 256 + threadIdx.x) * 8;
    float4 a = *reinterpret_cast<const float4*>(src + base);
    float4 b = *reinterpret_cast<const float4*>(src + base + 4);
    float f[8] = {a.x, a.y, a.z, a.w, b.x, b.y, b.z, b.w};
    unsigned short hb[8], lb[8];
    #pragma unroll
    for (int i = 0; i < 8; ++i) {
        hb[i] = f2bf(f[i]);
        lb[i] = f2bf(f[i] - bf2f(hb[i]));
    }
    *reinterpret_cast<uint4*>(dh + base) = *reinterpret_cast<const uint4*>(hb);
    if (z < 2)
        *reinterpret_cast<uint4*>(dl + base) = *reinterpret_cast<const uint4*>(lb);
}

// ---------------------------------------------------------------------------
// Prep 2: W[h][d][k] (f32) -> W^T[j=h*64+k][d] bf16 hi (+lo for Q,K).
// One block per (d-tile 64, head, tensor); LDS f32 transpose.
// ---------------------------------------------------------------------------
__global__ __launch_bounds__(256) void split_w(
    const float* __restrict__ Wq_, const float* __restrict__ Wk_, const float* __restrict__ Wv_,
    unsigned short* __restrict__ Wth0, unsigned short* __restrict__ Wth1, unsigned short* __restrict__ Wth2,
    unsigned short* __restrict__ Wtl0, unsigned short* __restrict__ Wtl1)
{
    const int z = blockIdx.z;
    const float* W = (z == 0) ? Wq_ : (z == 1) ? Wk_ : Wv_;
    unsigned short* oh = (z == 0) ? Wth0 : (z == 1) ? Wth1 : Wth2;
    unsigned short* ol = (z == 0) ? Wtl0 : (z == 1) ? Wtl1 : nullptr;
    const int h = blockIdx.y, dt = blockIdx.x;
    const int tid = threadIdx.x;

    __shared__ float lds[64][65];

    {   // load 64(d) x 64(k) f32 tile, coalesced
        int rr = tid >> 2, c4 = (tid & 3) * 16;
        const float* src = W + ((size_t)h * DMODEL + dt * 64 + rr) * DK + c4;
        #pragma unroll
        for (int i = 0; i < 4; ++i) {
            float4 v = *reinterpret_cast<const float4*>(src + i * 4);
            lds[rr][c4 + i * 4 + 0] = v.x;
            lds[rr][c4 + i * 4 + 1] = v.y;
            lds[rr][c4 + i * 4 + 2] = v.z;
            lds[rr][c4 + i * 4 + 3] = v.w;
        }
    }
    __syncthreads();
    {   // write transposed: row k, 16 d-values per thread
        int kk_ = tid >> 2, d4 = (tid & 3) * 16;
        unsigned short hb[16], lb[16];
        #pragma unroll
        for (int i = 0; i < 16; ++i) {
            float v = lds[d4 + i][kk_];
            hb[i] = f2bf(v);
            lb[i] = f2bf(v - bf2f(hb[i]));
        }
        size_t o = (size_t)(h * 64 + kk_) * DMODEL + dt * 64 + d4;
        *reinterpret_cast<uint4*>(oh + o)     = *reinterpret_cast<const uint4*>(hb);
        *reinterpret_cast<uint4*>(oh + o + 8) = *reinterpret_cast<const uint4*>(hb + 8);
        if (z < 2) {
            *reinterpret_cast<uint4*>(ol + o)     = *reinterpret_cast<const uint4*>(lb);
            *reinterpret_cast<uint4*>(ol + o + 8) = *reinterpret_cast<const uint4*>(lb + 8);
        }
    }
}

// ---------------------------------------------------------------------------
// Kernel 1: per-head input projections from pre-split bf16 operands.
// z=0,1 (Q,K): 3-term split-bf16 MFMA, writes hi/lo bf16 head-major.
// z=2   (V) : 1-term MFMA, writes bf16.
// GEMM tile 128x128, BK=64, 4 waves (2x2), each wave 64x64.
// ---------------------------------------------------------------------------
__global__ __launch_bounds__(256) void proj_kernel(
    const unsigned short* __restrict__ Ah0, const unsigned short* __restrict__ Ah1, const unsigned short* __restrict__ Ah2,
    const unsigned short* __restrict__ Al0, const unsigned short* __restrict__ Al1,
    const unsigned short* __restrict__ Wth0, const unsigned short* __restrict__ Wth1, const unsigned short* __restrict__ Wth2,
    const unsigned short* __restrict__ Wtl0, const unsigned short* __restrict__ Wtl1,
    const float* __restrict__ bq_, const float* __restrict__ bk_, const float* __restrict__ bv_,
    unsigned short* __restrict__ Qhh, unsigned short* __restrict__ Qhl,
    unsigned short* __restrict__ Khh, unsigned short* __restrict__ Khl,
    unsigned short* __restrict__ Vh)
{
    const int z = blockIdx.z;
    const unsigned short* Ah = (z == 0) ? Ah0 : (z == 1) ? Ah1 : Ah2;
    const unsigned short* Al = (z == 0) ? Al0 : Al1;
    const unsigned short* Bh = (z == 0) ? Wth0 : (z == 1) ? Wth1 : Wth2;
    const unsigned short* Bl = (z == 0) ? Wtl0 : Wtl1;
    const float* bias = (z == 0) ? bq_ : (z == 1) ? bk_ : bv_;

    __shared__ alignas(16) unsigned char sAh[16384];   // [128 rows][64 bf16] swizzled, hi
    __shared__ alignas(16) unsigned char sAl[16384];   // lo
    __shared__ alignas(16) unsigned char sBh[16384];   // [128 j][64 d] swizzled, hi
    __shared__ alignas(16) unsigned char sBl[16384];   // lo

    const int tid = threadIdx.x;
    const int lane = tid & 63;
    const int w = tid >> 6;               // 0..3
    const int wm = w >> 1, wn = w & 1;    // 2x2 wave grid
    const int g = lane >> 4, li = lane & 15;

    const int row0 = blockIdx.x * 128;    // token rows
    const int col0 = blockIdx.y * 128;    // output cols (h*64+k)

    f32x4 acc[4][4];
    #pragma unroll
    for (int m = 0; m < 4; ++m)
        #pragma unroll
        for (int n = 0; n < 4; ++n) acc[m][n] = f32x4{0.f, 0.f, 0.f, 0.f};

    for (int kt = 0; kt < DMODEL; kt += 64) {
        __syncthreads();
        #pragma unroll
        for (int p = 0; p < 4; ++p) {
            int c = p * 256 + tid;        // 0..1023
            int r = c >> 3, ch = c & 7;   // 128 rows x 8 chunks of 16B
            *reinterpret_cast<uint4*>(sAh + swz(r, ch * 16)) =
                *reinterpret_cast<const uint4*>(Ah + (size_t)(row0 + r) * DMODEL + kt + ch * 8);
            *reinterpret_cast<uint4*>(sBh + swz(r, ch * 16)) =
                *reinterpret_cast<const uint4*>(Bh + (size_t)(col0 + r) * DMODEL + kt + ch * 8);
            if (z < 2) {
                *reinterpret_cast<uint4*>(sAl + swz(r, ch * 16)) =
                    *reinterpret_cast<const uint4*>(Al + (size_t)(row0 + r) * DMODEL + kt + ch * 8);
                *reinterpret_cast<uint4*>(sBl + swz(r, ch * 16)) =
                    *reinterpret_cast<const uint4*>(Bl + (size_t)(col0 + r) * DMODEL + kt + ch * 8);
            }
        }
        __syncthreads();

        if (z < 2) {
            #pragma unroll
            for (int kk = 0; kk < 2; ++kk) {
                bfrag afh[4], afl[4], bfh[4], bfl[4];
                #pragma unroll
                for (int m = 0; m < 4; ++m) {
                    afh[m] = *reinterpret_cast<const bfrag*>(sAh + swz(wm * 64 + m * 16 + li, kk * 64 + g * 16));
                    afl[m] = *reinterpret_cast<const bfrag*>(sAl + swz(wm * 64 + m * 16 + li, kk * 64 + g * 16));
                }
                #pragma unroll
                for (int n = 0; n < 4; ++n) {
                    bfh[n] = *reinterpret_cast<const bfrag*>(sBh + swz(wn * 64 + n * 16 + li, kk * 64 + g * 16));
                    bfl[n] = *reinterpret_cast<const bfrag*>(sBl + swz(wn * 64 + n * 16 + li, kk * 64 + g * 16));
                }
                #pragma unroll
                for (int m = 0; m < 4; ++m)
                    #pragma unroll
                    for (int n = 0; n < 4; ++n) {
                        acc[m][n] = __builtin_amdgcn_mfma_f32_16x16x32_bf16(afh[m], bfh[n], acc[m][n], 0, 0, 0);
                        acc[m][n] = __builtin_amdgcn_mfma_f32_16x16x32_bf16(afl[m], bfh[n], acc[m][n], 0, 0, 0);
                        acc[m][n] = __builtin_amdgcn_mfma_f32_16x16x32_bf16(afh[m], bfl[n], acc[m][n], 0, 0, 0);
                    }
            }
        } else {
            #pragma unroll
            for (int kk = 0; kk < 2; ++kk) {
                bfrag afh[4], bfh[4];
                #pragma unroll
                for (int m = 0; m < 4; ++m)
                    afh[m] = *reinterpret_cast<const bfrag*>(sAh + swz(wm * 64 + m * 16 + li, kk * 64 + g * 16));
                #pragma unroll
                for (int n = 0; n < 4; ++n)
                    bfh[n] = *reinterpret_cast<const bfrag*>(sBh + swz(wn * 64 + n * 16 + li, kk * 64 + g * 16));
                #pragma unroll
                for (int m = 0; m < 4; ++m)
                    #pragma unroll
                    for (int n = 0; n < 4; ++n)
                        acc[m][n] = __builtin_amdgcn_mfma_f32_16x16x32_bf16(afh[m], bfh[n], acc[m][n], 0, 0, 0);
            }
        }
    }

    // epilogue: +bias; Q,K -> hi/lo bf16 head-major [h][n][k]; V -> bf16
    #pragma unroll
    for (int m = 0; m < 4; ++m) {
        #pragma unroll
        for (int n = 0; n < 4; ++n) {
            int colg = col0 + wn * 64 + n * 16 + li;
            float bb = bias[colg];
            int hh = colg >> 6, k = colg & 63;
            #pragma unroll
            for (int r = 0; r < 4; ++r) {
                int rowg = row0 + wm * 64 + m * 16 + g * 4 + r;
                size_t o = ((size_t)hh * N_TOK + rowg) * DK + k;
                float val = acc[m][n][r] + bb;
                if (z == 2) {
                    Vh[o] = f2bf(val);
                } else {
                    unsigned short hb = f2bf(val);
                    unsigned short lb = f2bf(val - bf2f(hb));
                    if (z == 0) { Qhh[o] = hb; Qhl[o] = lb; }
                    else        { Khh[o] = hb; Khl[o] = lb; }
                }
            }
        }
    }
}

// ---------------------------------------------------------------------------
// Kernel 2: flash attention per (q-tile, head). 8 waves x 16 q-rows, KV tile 64.
// Q,K pre-split hi/lo bf16 -> 3-MFMA QK^T for ~f32 score accuracy.
// softmax scale d_k^-0.5 applied post-softmax (== scale final O by 0.125/l).
// ---------------------------------------------------------------------------
__global__ __launch_bounds__(512) void attn_kernel(
    const unsigned short* __restrict__ Qhh, const unsigned short* __restrict__ Qhl,
    const unsigned short* __restrict__ Khh, const unsigned short* __restrict__ Khl,
    const unsigned short* __restrict__ Vh,
    unsigned short* __restrict__ Hc)
{
    __shared__ alignas(16) unsigned char sKh[8192];   // [64 key][64 k] swizzled, hi
    __shared__ alignas(16) unsigned char sKl[8192];   // lo
    __shared__ alignas(16) unsigned char sV[8192];    // [64 v ][64 key] swizzled (V^T)
    __shared__ alignas(16) unsigned char sP[16384];   // per-wave 16x64 P tiles

    const int tid = threadIdx.x;
    const int lane = tid & 63;
    const int w = tid >> 6;               // 0..7
    const int g = lane >> 4, li = lane & 15;
    const int h = blockIdx.y;
    const int qrow0 = blockIdx.x * 128 + w * 16;

    const unsigned short* QbaseH = Qhh + (size_t)h * N_TOK * DK;
    const unsigned short* QbaseL = Qhl + (size_t)h * N_TOK * DK;
    const unsigned short* KbaseH = Khh + (size_t)h * N_TOK * DK;
    const unsigned short* KbaseL = Khl + (size_t)h * N_TOK * DK;
    const unsigned short* Vbase  = Vh  + (size_t)h * N_TOK * DK;
    unsigned char* sPw = sP + w * 2048;

    // Q fragments (hi/lo) held in registers for the whole kernel
    bfrag aqh[2], aql[2];
    #pragma unroll
    for (int kk = 0; kk < 2; ++kk) {
        size_t o = (size_t)(qrow0 + li) * DK + kk * 32 + g * 8;
        aqh[kk] = *reinterpret_cast<const bfrag*>(QbaseH + o);
        aql[kk] = *reinterpret_cast<const bfrag*>(QbaseL + o);
    }

    f32x4 accO[4];
    #pragma unroll
    for (int n = 0; n < 4; ++n) accO[n] = f32x4{0.f, 0.f, 0.f, 0.f};
    float mrun[4], lrun[4];
    #pragma unroll
    for (int r = 0; r < 4; ++r) { mrun[r] = -3.0e38f; lrun[r] = 0.f; }

    for (int t = 0; t < N_TOK; t += 64) {
        __syncthreads();
        {   // stage K tile hi/lo (pre-split): plain 16B copies, swizzled
            int r = tid >> 3;
            int cq = tid & 7;
            size_t o = (size_t)(t + r) * DK + cq * 8;
            *reinterpret_cast<uint4*>(sKh + swz(r, cq * 16)) =
                *reinterpret_cast<const uint4*>(KbaseH + o);
            *reinterpret_cast<uint4*>(sKl + swz(r, cq * 16)) =
                *reinterpret_cast<const uint4*>(KbaseL + o);
        }
        {   // stage V^T: lane<->row mapping keeps the 2B scatter conflict-free
            int mr = tid & 63;
            int v0 = (tid >> 6) * 8;
            bfrag vv = *reinterpret_cast<const bfrag*>(Vbase + (size_t)(t + mr) * DK + v0);
            #pragma unroll
            for (int e = 0; e < 8; ++e)
                *reinterpret_cast<unsigned short*>(sV + swz(v0 + e, mr * 2)) = (unsigned short)vv[e];
        }
        __syncthreads();

        // S = Q K^T  (16 q-rows x 64 keys per wave), split-bf16 3-MFMA
        f32x4 s[4];
        #pragma unroll
        for (int n = 0; n < 4; ++n) s[n] = f32x4{0.f, 0.f, 0.f, 0.f};
        #pragma unroll
        for (int kk = 0; kk < 2; ++kk) {
            #pragma unroll
            for (int n = 0; n < 4; ++n) {
                bfrag bkh = *reinterpret_cast<const bfrag*>(sKh + swz(n * 16 + li, kk * 64 + g * 16));
                bfrag bkl = *reinterpret_cast<const bfrag*>(sKl + swz(n * 16 + li, kk * 64 + g * 16));
                s[n] = __builtin_amdgcn_mfma_f32_16x16x32_bf16(aqh[kk], bkh, s[n], 0, 0, 0);
                s[n] = __builtin_amdgcn_mfma_f32_16x16x32_bf16(aql[kk], bkh, s[n], 0, 0, 0);
                s[n] = __builtin_amdgcn_mfma_f32_16x16x32_bf16(aqh[kk], bkl, s[n], 0, 0, 0);
            }
        }

        // online softmax; row r of this lane = qrow0 + g*4 + r, cols across 16 lanes
        float tmax[4];
        #pragma unroll
        for (int r = 0; r < 4; ++r)
            tmax[r] = fmaxf(fmaxf(s[0][r], s[1][r]), fmaxf(s[2][r], s[3][r]));
        #pragma unroll
        for (int off = 1; off < 16; off <<= 1)
            #pragma unroll
            for (int r = 0; r < 4; ++r)
                tmax[r] = fmaxf(tmax[r], __shfl_xor(tmax[r], off));
        float sc[4];
        #pragma unroll
        for (int r = 0; r < 4; ++r) {
            float nm = fmaxf(mrun[r], tmax[r]);
            sc[r] = __expf(mrun[r] - nm);
            mrun[r] = nm;
            lrun[r] *= sc[r];
        }
        #pragma unroll
        for (int n = 0; n < 4; ++n)
            #pragma unroll
            for (int r = 0; r < 4; ++r)
                accO[n][r] *= sc[r];

        float psum[4] = {0.f, 0.f, 0.f, 0.f};
        #pragma unroll
        for (int n = 0; n < 4; ++n) {
            #pragma unroll
            for (int r = 0; r < 4; ++r) {
                float p = __expf(s[n][r] - mrun[r]);
                unsigned short pb = f2bf(p);
                psum[r] += bf2f(pb);       // sum the SAME rounded values PV uses
                *reinterpret_cast<unsigned short*>(sPw + swz(g * 4 + r, (n * 16 + li) * 2)) = pb;
            }
        }
        #pragma unroll
        for (int off = 1; off < 16; off <<= 1)
            #pragma unroll
            for (int r = 0; r < 4; ++r)
                psum[r] += __shfl_xor(psum[r], off);
        #pragma unroll
        for (int r = 0; r < 4; ++r) lrun[r] += psum[r];

        // O += P @ V_tile  (P re-read from LDS in A-fragment layout)
        #pragma unroll
        for (int kk = 0; kk < 2; ++kk) {
            bfrag pa = *reinterpret_cast<const bfrag*>(sPw + swz(li, kk * 64 + g * 16));
            #pragma unroll
            for (int n = 0; n < 4; ++n) {
                bfrag vb = *reinterpret_cast<const bfrag*>(sV + swz(n * 16 + li, kk * 64 + g * 16));
                accO[n] = __builtin_amdgcn_mfma_f32_16x16x32_bf16(pa, vb, accO[n], 0, 0, 0);
            }
        }
    }

    // epilogue: O * (d_k^-0.5 / l) -> concat buffer [n][h*64+v] (bf16)
    #pragma unroll
    for (int r = 0; r < 4; ++r) {
        float inv = 0.125f / lrun[r];
        int rowg = qrow0 + g * 4 + r;
        #pragma unroll
        for (int n = 0; n < 4; ++n) {
            int colg = h * 64 + n * 16 + li;
            Hc[(size_t)rowg * (NH * DK) + colg] = f2bf(accO[n][r] * inv);
        }
    }
}

// ---------------------------------------------------------------------------
// Kernel 3: output projection. out = Hc(bf16 2048x1024) @ Wo(f32 1024x1024) + bo
// tile 128x64, BK=64, 4 waves (each 32 rows x 64 cols).
// ---------------------------------------------------------------------------
__global__ __launch_bounds__(256) void oproj_kernel(
    const unsigned short* __restrict__ Hc,
    const float* __restrict__ Wo,
    const float* __restrict__ bo,
    float* __restrict__ out)
{
    __shared__ alignas(16) unsigned char sA[16384];   // [128][64] bf16 swizzled
    __shared__ alignas(16) unsigned char sB[8192];    // [64 j][64 d] swizzled (Wo^T)

    const int tid = threadIdx.x;
    const int lane = tid & 63;
    const int w = tid >> 6;               // 0..3, rows w*32..+32
    const int g = lane >> 4, li = lane & 15;
    const int row0 = blockIdx.x * 128;
    const int col0 = blockIdx.y * 64;

    f32x4 acc[2][4];
    #pragma unroll
    for (int m = 0; m < 2; ++m)
        #pragma unroll
        for (int n = 0; n < 4; ++n) acc[m][n] = f32x4{0.f, 0.f, 0.f, 0.f};

    for (int kt = 0; kt < DMODEL; kt += 64) {
        __syncthreads();
        // stage A (already bf16): linear 16B chunks
        #pragma unroll
        for (int p = 0; p < 4; ++p) {
            int c = p * 256 + tid;            // 0..1023
            int r = c >> 3, off = (c & 7) * 16;
            *reinterpret_cast<uint4*>(sA + swz(r, off)) =
                *reinterpret_cast<const uint4*>(Hc + (size_t)(row0 + r) * DMODEL + kt + (c & 7) * 8);
        }
        // stage Wo^T tile: Wo[d][j] -> sB[j][d], 4x4 register transpose
        {
            int dq = tid & 15;                // d = dq*4..+3
            int j4 = tid >> 4;                // j = j4*4..+3, 0..15
            int j = j4 * 4;
            const float* src = Wo + (size_t)(kt + dq * 4) * DMODEL + col0 + j;
            float4 r0 = *reinterpret_cast<const float4*>(src);
            float4 r1 = *reinterpret_cast<const float4*>(src + DMODEL);
            float4 r2 = *reinterpret_cast<const float4*>(src + 2 * DMODEL);
            float4 r3 = *reinterpret_cast<const float4*>(src + 3 * DMODEL);
            unsigned short e[16] = {
                f2bf(r0.x), f2bf(r1.x), f2bf(r2.x), f2bf(r3.x),
                f2bf(r0.y), f2bf(r1.y), f2bf(r2.y), f2bf(r3.y),
                f2bf(r0.z), f2bf(r1.z), f2bf(r2.z), f2bf(r3.z),
                f2bf(r0.w), f2bf(r1.w), f2bf(r2.w), f2bf(r3.w)};
            #pragma unroll
            for (int q = 0; q < 4; ++q)
                *reinterpret_cast<uint2*>(sB + swz(j + q, dq * 8)) =
                    *reinterpret_cast<const uint2*>(e + q * 4);
        }
        __syncthreads();

        #pragma unroll
        for (int kk = 0; kk < 2; ++kk) {
            bfrag af[2], bf_[4];
            #pragma unroll
            for (int m = 0; m < 2; ++m)
                af[m] = *reinterpret_cast<const bfrag*>(sA + swz(w * 32 + m * 16 + li, kk * 64 + g * 16));
            #pragma unroll
            for (int n = 0; n < 4; ++n)
                bf_[n] = *reinterpret_cast<const bfrag*>(sB + swz(n * 16 + li, kk * 64 + g * 16));
            #pragma unroll
            for (int m = 0; m < 2; ++m)
                #pragma unroll
                for (int n = 0; n < 4; ++n)
                    acc[m][n] = __builtin_amdgcn_mfma_f32_16x16x32_bf16(af[m], bf_[n], acc[m][n], 0, 0, 0);
        }
    }

    #pragma unroll
    for (int m = 0; m < 2; ++m) {
        #pragma unroll
        for (int n = 0; n < 4; ++n) {
            int colg = col0 + n * 16 + li;
            float bb = bo[colg];
            #pragma unroll
            for (int r = 0; r < 4; ++r) {
                int rowg = row0 + w * 32 + m * 16 + g * 4 + r;
                out[(size_t)rowg * DMODEL + colg] = acc[m][n][r] + bb;
            }
        }
    }
}

extern "C" void kernel_launch(void* const* d_in, const int* in_sizes, int n_in,
                              void* d_out, int out_size, void* d_ws, size_t ws_size,
                              hipStream_t stream) {
    (void)in_sizes; (void)n_in; (void)out_size; (void)ws_size;
    const float* Q  = (const float*)d_in[0];
    const float* K  = (const float*)d_in[1];
    const float* V  = (const float*)d_in[2];
    // d_in[3] = mask (unused by reference forward)
    const float* Wq = (const float*)d_in[4];
    const float* bq = (const float*)d_in[5];
    const float* Wk = (const float*)d_in[6];
    const float* bk = (const float*)d_in[7];
    const float* Wv = (const float*)d_in[8];
    const float* bv = (const float*)d_in[9];
    const float* Wo = (const float*)d_in[10];
    const float* bo = (const float*)d_in[11];
    float* out = (float*)d_out;

    const size_t ASZ = (size_t)N_TOK * DMODEL;   // 2M elems
    const size_t WSZ = (size_t)NH * DK * DMODEL; // 1M elems
    const size_t HSZ = (size_t)NH * N_TOK * DK;  // 2M elems
    unsigned short* p = (unsigned short*)d_ws;
    unsigned short* Ah0 = p; p += ASZ;
    unsigned short* Ah1 = p; p += ASZ;
    unsigned short* Ah2 = p; p += ASZ;
    unsigned short* Al0 = p; p += ASZ;
    unsigned short* Al1 = p; p += ASZ;
    unsigned short* Wth0 = p; p += WSZ;
    unsigned short* Wth1 = p; p += WSZ;
    unsigned short* Wth2 = p; p += WSZ;
    unsigned short* Wtl0 = p; p += WSZ;
    unsigned short* Wtl1 = p; p += WSZ;
    unsigned short* Qhh = p; p += HSZ;
    unsigned short* Qhl = p; p += HSZ;
    unsigned short* Khh = p; p += HSZ;
    unsigned short* Khl = p; p += HSZ;
    unsigned short* Vh  = p; p += HSZ;
    unsigned short* Hc  = p; p += HSZ;

    split_act<<<dim3(1024, 3), 256, 0, stream>>>(Q, K, V, Ah0, Ah1, Ah2, Al0, Al1);
    split_w<<<dim3(16, 16, 3), 256, 0, stream>>>(Wq, Wk, Wv, Wth0, Wth1, Wth2, Wtl0, Wtl1);
    proj_kernel<<<dim3(16, 8, 3), 256, 0, stream>>>(
        Ah0, Ah1, Ah2, Al0, Al1, Wth0, Wth1, Wth2, Wtl0, Wtl1,
        bq, bk, bv, Qhh, Qhl, Khh, Khl, Vh);
    attn_kernel<<<dim3(16, 16), 512, 0, stream>>>(Qhh, Qhl, Khh, Khl, Vh, Hc);
    oproj_kernel<<<dim3(16, 16), 256, 0, stream>>>(Hc, Wo, bo, out);
}

// Round 4
// 168.916 us; speedup vs baseline: 1.3864x; 1.1678x over previous
//
#include <hip/hip_runtime.h>

#define N_TOK 2048
#define DMODEL 1024
#define NH 16
#define DK 64

typedef __attribute__((ext_vector_type(8))) short bfrag;   // 8 bf16 = one MFMA A/B operand
typedef __attribute__((ext_vector_type(4))) float f32x4;   // MFMA C/D

__device__ __forceinline__ unsigned short f2bf(float f) {
    unsigned u = __builtin_bit_cast(unsigned, f);
    u += 0x7FFFu + ((u >> 16) & 1u);          // round-to-nearest-even
    return (unsigned short)(u >> 16);
}
__device__ __forceinline__ float bf2f(unsigned short u) {
    unsigned x = ((unsigned)u) << 16;
    return __builtin_bit_cast(float, x);
}

// swizzled byte offset inside a [rows][64 bf16] LDS tile (128 B rows).
__device__ __forceinline__ int swz(int row, int b) {
    return row * 128 + (b ^ ((row & 7) << 4));
}

// async global->LDS 16B: LDS dest must be wave-uniform base (+ lane*16 by HW);
// global src is per-lane (carries the inverse swizzle).
__device__ __forceinline__ void gload16(const void* g, void* l) {
    __builtin_amdgcn_global_load_lds(
        (__attribute__((address_space(1))) void*)g,
        (__attribute__((address_space(3))) void*)l,
        16, 0, 0);
}

// ---------------------------------------------------------------------------
// Prep 1: split activations Q,K,V (f32 row-major [2048][1024]) into bf16
// hi (all) and lo (Q,K only) row-major arrays.
// ---------------------------------------------------------------------------
__global__ __launch_bounds__(256) void split_act(
    const float* __restrict__ Qin, const float* __restrict__ Kin, const float* __restrict__ Vin,
    unsigned short* __restrict__ Ah0, unsigned short* __restrict__ Ah1, unsigned short* __restrict__ Ah2,
    unsigned short* __restrict__ Al0, unsigned short* __restrict__ Al1)
{
    const int z = blockIdx.y;
    const float* src = (z == 0) ? Qin : (z == 1) ? Kin : Vin;
    unsigned short* dh = (z == 0) ? Ah0 : (z == 1) ? Ah1 : Ah2;
    unsigned short* dl = (z == 0) ? Al0 : (z == 1) ? Al1 : nullptr;

    size_t base = ((size_t)blockIdx.x * 256 + threadIdx.x) * 8;
    float4 a = *reinterpret_cast<const float4*>(src + base);
    float4 b = *reinterpret_cast<const float4*>(src + base + 4);
    float f[8] = {a.x, a.y, a.z, a.w, b.x, b.y, b.z, b.w};
    unsigned short hb[8], lb[8];
    #pragma unroll
    for (int i = 0; i < 8; ++i) {
        hb[i] = f2bf(f[i]);
        lb[i] = f2bf(f[i] - bf2f(hb[i]));
    }
    *reinterpret_cast<uint4*>(dh + base) = *reinterpret_cast<const uint4*>(hb);
    if (z < 2)
        *reinterpret_cast<uint4*>(dl + base) = *reinterpret_cast<const uint4*>(lb);
}

// ---------------------------------------------------------------------------
// Prep 2: W[h][d][k] (f32) -> W^T[j=h*64+k][d] bf16 hi (+lo for Q,K).
// ---------------------------------------------------------------------------
__global__ __launch_bounds__(256) void split_w(
    const float* __restrict__ Wq_, const float* __restrict__ Wk_, const float* __restrict__ Wv_,
    unsigned short* __restrict__ Wth0, unsigned short* __restrict__ Wth1, unsigned short* __restrict__ Wth2,
    unsigned short* __restrict__ Wtl0, unsigned short* __restrict__ Wtl1)
{
    const int z = blockIdx.z;
    const float* W = (z == 0) ? Wq_ : (z == 1) ? Wk_ : Wv_;
    unsigned short* oh = (z == 0) ? Wth0 : (z == 1) ? Wth1 : Wth2;
    unsigned short* ol = (z == 0) ? Wtl0 : (z == 1) ? Wtl1 : nullptr;
    const int h = blockIdx.y, dt = blockIdx.x;
    const int tid = threadIdx.x;

    __shared__ float lds[64][65];

    {   // load 64(d) x 64(k) f32 tile, coalesced
        int rr = tid >> 2, c4 = (tid & 3) * 16;
        const float* src = W + ((size_t)h * DMODEL + dt * 64 + rr) * DK + c4;
        #pragma unroll
        for (int i = 0; i < 4; ++i) {
            float4 v = *reinterpret_cast<const float4*>(src + i * 4);
            lds[rr][c4 + i * 4 + 0] = v.x;
            lds[rr][c4 + i * 4 + 1] = v.y;
            lds[rr][c4 + i * 4 + 2] = v.z;
            lds[rr][c4 + i * 4 + 3] = v.w;
        }
    }
    __syncthreads();
    {   // write transposed: row k, 16 d-values per thread
        int kk_ = tid >> 2, d4 = (tid & 3) * 16;
        unsigned short hb[16], lb[16];
        #pragma unroll
        for (int i = 0; i < 16; ++i) {
            float v = lds[d4 + i][kk_];
            hb[i] = f2bf(v);
            lb[i] = f2bf(v - bf2f(hb[i]));
        }
        size_t o = (size_t)(h * 64 + kk_) * DMODEL + dt * 64 + d4;
        *reinterpret_cast<uint4*>(oh + o)     = *reinterpret_cast<const uint4*>(hb);
        *reinterpret_cast<uint4*>(oh + o + 8) = *reinterpret_cast<const uint4*>(hb + 8);
        if (z < 2) {
            *reinterpret_cast<uint4*>(ol + o)     = *reinterpret_cast<const uint4*>(lb);
            *reinterpret_cast<uint4*>(ol + o + 8) = *reinterpret_cast<const uint4*>(lb + 8);
        }
    }
}

// ---------------------------------------------------------------------------
// Kernel 1: per-head input projections from pre-split bf16 operands.
// z=0,1 (Q,K): 3-term split-bf16 MFMA -> hi/lo bf16 head-major [h][n][k].
// z=2   (V) : 1-term MFMA -> bf16 TRANSPOSED per head: Vt[h][dv][token].
// ---------------------------------------------------------------------------
__global__ __launch_bounds__(256) void proj_kernel(
    const unsigned short* __restrict__ Ah0, const unsigned short* __restrict__ Ah1, const unsigned short* __restrict__ Ah2,
    const unsigned short* __restrict__ Al0, const unsigned short* __restrict__ Al1,
    const unsigned short* __restrict__ Wth0, const unsigned short* __restrict__ Wth1, const unsigned short* __restrict__ Wth2,
    const unsigned short* __restrict__ Wtl0, const unsigned short* __restrict__ Wtl1,
    const float* __restrict__ bq_, const float* __restrict__ bk_, const float* __restrict__ bv_,
    unsigned short* __restrict__ Qhh, unsigned short* __restrict__ Qhl,
    unsigned short* __restrict__ Khh, unsigned short* __restrict__ Khl,
    unsigned short* __restrict__ Vt)
{
    const int z = blockIdx.z;
    const unsigned short* Ah = (z == 0) ? Ah0 : (z == 1) ? Ah1 : Ah2;
    const unsigned short* Al = (z == 0) ? Al0 : Al1;
    const unsigned short* Bh = (z == 0) ? Wth0 : (z == 1) ? Wth1 : Wth2;
    const unsigned short* Bl = (z == 0) ? Wtl0 : Wtl1;
    const float* bias = (z == 0) ? bq_ : (z == 1) ? bk_ : bv_;

    __shared__ alignas(16) unsigned char sAh[16384];   // [128 rows][64 bf16] swizzled, hi
    __shared__ alignas(16) unsigned char sAl[16384];   // lo
    __shared__ alignas(16) unsigned char sBh[16384];   // [128 j][64 d] swizzled, hi
    __shared__ alignas(16) unsigned char sBl[16384];   // lo

    const int tid = threadIdx.x;
    const int lane = tid & 63;
    const int w = tid >> 6;               // 0..3
    const int wm = w >> 1, wn = w & 1;    // 2x2 wave grid
    const int g = lane >> 4, li = lane & 15;

    const int row0 = blockIdx.x * 128;    // token rows
    const int col0 = blockIdx.y * 128;    // output cols (h*64+k)

    f32x4 acc[4][4];
    #pragma unroll
    for (int m = 0; m < 4; ++m)
        #pragma unroll
        for (int n = 0; n < 4; ++n) acc[m][n] = f32x4{0.f, 0.f, 0.f, 0.f};

    for (int kt = 0; kt < DMODEL; kt += 64) {
        __syncthreads();
        #pragma unroll
        for (int p = 0; p < 4; ++p) {
            int c = p * 256 + tid;        // 0..1023
            int r = c >> 3, ch = c & 7;   // 128 rows x 8 chunks of 16B
            *reinterpret_cast<uint4*>(sAh + swz(r, ch * 16)) =
                *reinterpret_cast<const uint4*>(Ah + (size_t)(row0 + r) * DMODEL + kt + ch * 8);
            *reinterpret_cast<uint4*>(sBh + swz(r, ch * 16)) =
                *reinterpret_cast<const uint4*>(Bh + (size_t)(col0 + r) * DMODEL + kt + ch * 8);
            if (z < 2) {
                *reinterpret_cast<uint4*>(sAl + swz(r, ch * 16)) =
                    *reinterpret_cast<const uint4*>(Al + (size_t)(row0 + r) * DMODEL + kt + ch * 8);
                *reinterpret_cast<uint4*>(sBl + swz(r, ch * 16)) =
                    *reinterpret_cast<const uint4*>(Bl + (size_t)(col0 + r) * DMODEL + kt + ch * 8);
            }
        }
        __syncthreads();

        if (z < 2) {
            #pragma unroll
            for (int kk = 0; kk < 2; ++kk) {
                bfrag afh[4], afl[4], bfh[4], bfl[4];
                #pragma unroll
                for (int m = 0; m < 4; ++m) {
                    afh[m] = *reinterpret_cast<const bfrag*>(sAh + swz(wm * 64 + m * 16 + li, kk * 64 + g * 16));
                    afl[m] = *reinterpret_cast<const bfrag*>(sAl + swz(wm * 64 + m * 16 + li, kk * 64 + g * 16));
                }
                #pragma unroll
                for (int n = 0; n < 4; ++n) {
                    bfh[n] = *reinterpret_cast<const bfrag*>(sBh + swz(wn * 64 + n * 16 + li, kk * 64 + g * 16));
                    bfl[n] = *reinterpret_cast<const bfrag*>(sBl + swz(wn * 64 + n * 16 + li, kk * 64 + g * 16));
                }
                #pragma unroll
                for (int m = 0; m < 4; ++m)
                    #pragma unroll
                    for (int n = 0; n < 4; ++n) {
                        acc[m][n] = __builtin_amdgcn_mfma_f32_16x16x32_bf16(afh[m], bfh[n], acc[m][n], 0, 0, 0);
                        acc[m][n] = __builtin_amdgcn_mfma_f32_16x16x32_bf16(afl[m], bfh[n], acc[m][n], 0, 0, 0);
                        acc[m][n] = __builtin_amdgcn_mfma_f32_16x16x32_bf16(afh[m], bfl[n], acc[m][n], 0, 0, 0);
                    }
            }
        } else {
            #pragma unroll
            for (int kk = 0; kk < 2; ++kk) {
                bfrag afh[4], bfh[4];
                #pragma unroll
                for (int m = 0; m < 4; ++m)
                    afh[m] = *reinterpret_cast<const bfrag*>(sAh + swz(wm * 64 + m * 16 + li, kk * 64 + g * 16));
                #pragma unroll
                for (int n = 0; n < 4; ++n)
                    bfh[n] = *reinterpret_cast<const bfrag*>(sBh + swz(wn * 64 + n * 16 + li, kk * 64 + g * 16));
                #pragma unroll
                for (int m = 0; m < 4; ++m)
                    #pragma unroll
                    for (int n = 0; n < 4; ++n)
                        acc[m][n] = __builtin_amdgcn_mfma_f32_16x16x32_bf16(afh[m], bfh[n], acc[m][n], 0, 0, 0);
            }
        }
    }

    // epilogue: +bias; Q,K -> hi/lo bf16 head-major; V -> bf16 transposed
    #pragma unroll
    for (int m = 0; m < 4; ++m) {
        #pragma unroll
        for (int n = 0; n < 4; ++n) {
            int colg = col0 + wn * 64 + n * 16 + li;
            float bb = bias[colg];
            int hh = colg >> 6, k = colg & 63;
            int rowb = row0 + wm * 64 + m * 16 + g * 4;
            if (z == 2) {
                unsigned short vb4[4];
                #pragma unroll
                for (int r = 0; r < 4; ++r) vb4[r] = f2bf(acc[m][n][r] + bb);
                *reinterpret_cast<uint2*>(Vt + ((size_t)hh * DK + k) * N_TOK + rowb) =
                    *reinterpret_cast<const uint2*>(vb4);
            } else {
                #pragma unroll
                for (int r = 0; r < 4; ++r) {
                    size_t o = ((size_t)hh * N_TOK + rowb + r) * DK + k;
                    float val = acc[m][n][r] + bb;
                    unsigned short hb = f2bf(val);
                    unsigned short lb = f2bf(val - bf2f(hb));
                    if (z == 0) { Qhh[o] = hb; Qhl[o] = lb; }
                    else        { Khh[o] = hb; Khl[o] = lb; }
                }
            }
        }
    }
}

// ---------------------------------------------------------------------------
// Kernel 2: flash attention, KV-split. Grid 1024 blocks (32 qtile x 16 head x
// 2 kv-half, XCD-swizzled), 4 waves x 16 q-rows, KV tile 64, 16 tiles/block.
// K hi/lo + V^T staged via global_load_lds (linear dest, pre-swizzled src).
// Writes unnormalized partial O (f32) + (m,l) per row; combine_kernel merges.
// ---------------------------------------------------------------------------
__global__ __launch_bounds__(256) void attn_kernel(
    const unsigned short* __restrict__ Qhh, const unsigned short* __restrict__ Qhl,
    const unsigned short* __restrict__ Khh, const unsigned short* __restrict__ Khl,
    const unsigned short* __restrict__ Vt,
    float* __restrict__ Opart, float* __restrict__ mlbuf)
{
    __shared__ alignas(16) unsigned char sKh[8192];   // [64 key][64 k] swizzled, hi
    __shared__ alignas(16) unsigned char sKl[8192];   // lo
    __shared__ alignas(16) unsigned char sV[8192];    // [64 dv][64 key] swizzled
    __shared__ alignas(16) unsigned char sP[8192];    // per-wave 16x64 P tiles

    // XCD swizzle: 128-block contiguous chunks per XCD (2 heads' K/V per L2)
    const int bid = blockIdx.x;                  // 0..1023
    const int orig = (bid & 7) * 128 + (bid >> 3);
    const int h    = orig >> 6;
    const int half = (orig >> 5) & 1;
    const int qt   = orig & 31;

    const int tid = threadIdx.x;
    const int lane = tid & 63;
    const int w = tid >> 6;               // 0..3
    const int g = lane >> 4, li = lane & 15;
    const int qrow0 = qt * 64 + w * 16;

    const unsigned short* QbH = Qhh + (size_t)h * N_TOK * DK;
    const unsigned short* QbL = Qhl + (size_t)h * N_TOK * DK;
    const unsigned short* KbH = Khh + (size_t)h * N_TOK * DK;
    const unsigned short* KbL = Khl + (size_t)h * N_TOK * DK;
    const unsigned short* Vtb = Vt  + (size_t)h * DK * N_TOK;
    unsigned char* sPw = sP + w * 2048;

    // Q fragments (hi/lo) held in registers
    bfrag aqh[2], aql[2];
    #pragma unroll
    for (int kk = 0; kk < 2; ++kk) {
        size_t o = (size_t)(qrow0 + li) * DK + kk * 32 + g * 8;
        aqh[kk] = *reinterpret_cast<const bfrag*>(QbH + o);
        aql[kk] = *reinterpret_cast<const bfrag*>(QbL + o);
    }

    f32x4 accO[4];
    #pragma unroll
    for (int n = 0; n < 4; ++n) accO[n] = f32x4{0.f, 0.f, 0.f, 0.f};
    float mrun[4], lrun[4];
    #pragma unroll
    for (int r = 0; r < 4; ++r) { mrun[r] = -3.0e38f; lrun[r] = 0.f; }

    for (int tt = 0; tt < 16; ++tt) {
        const int t = half * 1024 + tt * 64;
        __syncthreads();                       // previous tile fully consumed
        // stage K hi/lo + V^T via global_load_lds (2 passes x 3 buffers)
        #pragma unroll
        for (int p = 0; p < 2; ++p) {
            int chunk = p * 256 + w * 64 + lane;      // 16B chunk index, 0..511
            int r = chunk >> 3;                       // tile row
            int cs = ((chunk & 7) * 8) ^ ((r & 7) << 3);  // pre-swizzled short offset
            int ldso = (p * 256 + w * 64) * 16;       // wave-uniform LDS base
            gload16(KbH + (size_t)(t + r) * DK + cs, sKh + ldso);
            gload16(KbL + (size_t)(t + r) * DK + cs, sKl + ldso);
            gload16(Vtb + (size_t)r * N_TOK + t + cs, sV + ldso);
        }
        __syncthreads();                       // vmcnt drained before barrier

        // S = Q K^T  (16 q-rows x 64 keys per wave), split-bf16 3-MFMA
        f32x4 s[4];
        #pragma unroll
        for (int n = 0; n < 4; ++n) s[n] = f32x4{0.f, 0.f, 0.f, 0.f};
        #pragma unroll
        for (int kk = 0; kk < 2; ++kk) {
            #pragma unroll
            for (int n = 0; n < 4; ++n) {
                bfrag bkh = *reinterpret_cast<const bfrag*>(sKh + swz(n * 16 + li, kk * 64 + g * 16));
                bfrag bkl = *reinterpret_cast<const bfrag*>(sKl + swz(n * 16 + li, kk * 64 + g * 16));
                s[n] = __builtin_amdgcn_mfma_f32_16x16x32_bf16(aqh[kk], bkh, s[n], 0, 0, 0);
                s[n] = __builtin_amdgcn_mfma_f32_16x16x32_bf16(aql[kk], bkh, s[n], 0, 0, 0);
                s[n] = __builtin_amdgcn_mfma_f32_16x16x32_bf16(aqh[kk], bkl, s[n], 0, 0, 0);
            }
        }

        // online softmax; row r of this lane = qrow0 + g*4 + r
        float tmax[4];
        #pragma unroll
        for (int r = 0; r < 4; ++r)
            tmax[r] = fmaxf(fmaxf(s[0][r], s[1][r]), fmaxf(s[2][r], s[3][r]));
        #pragma unroll
        for (int off = 1; off < 16; off <<= 1)
            #pragma unroll
            for (int r = 0; r < 4; ++r)
                tmax[r] = fmaxf(tmax[r], __shfl_xor(tmax[r], off));
        float sc[4];
        #pragma unroll
        for (int r = 0; r < 4; ++r) {
            float nm = fmaxf(mrun[r], tmax[r]);
            sc[r] = __expf(mrun[r] - nm);
            mrun[r] = nm;
            lrun[r] *= sc[r];
        }
        #pragma unroll
        for (int n = 0; n < 4; ++n)
            #pragma unroll
            for (int r = 0; r < 4; ++r)
                accO[n][r] *= sc[r];

        float psum[4] = {0.f, 0.f, 0.f, 0.f};
        #pragma unroll
        for (int n = 0; n < 4; ++n) {
            #pragma unroll
            for (int r = 0; r < 4; ++r) {
                float p = __expf(s[n][r] - mrun[r]);
                unsigned short pb = f2bf(p);
                psum[r] += bf2f(pb);       // sum the SAME rounded values PV uses
                *reinterpret_cast<unsigned short*>(sPw + swz(g * 4 + r, (n * 16 + li) * 2)) = pb;
            }
        }
        #pragma unroll
        for (int off = 1; off < 16; off <<= 1)
            #pragma unroll
            for (int r = 0; r < 4; ++r)
                psum[r] += __shfl_xor(psum[r], off);
        #pragma unroll
        for (int r = 0; r < 4; ++r) lrun[r] += psum[r];

        // O += P @ V_tile
        #pragma unroll
        for (int kk = 0; kk < 2; ++kk) {
            bfrag pa = *reinterpret_cast<const bfrag*>(sPw + swz(li, kk * 64 + g * 16));
            #pragma unroll
            for (int n = 0; n < 4; ++n) {
                bfrag vb = *reinterpret_cast<const bfrag*>(sV + swz(n * 16 + li, kk * 64 + g * 16));
                accO[n] = __builtin_amdgcn_mfma_f32_16x16x32_bf16(pa, vb, accO[n], 0, 0, 0);
            }
        }
    }

    // epilogue: unnormalized partial O (f32) + per-row (m,l)
    const size_t pbase = (size_t)half * NH * N_TOK;
    #pragma unroll
    for (int r = 0; r < 4; ++r) {
        int row = qrow0 + g * 4 + r;
        size_t idxp = pbase + (size_t)h * N_TOK + row;
        #pragma unroll
        for (int n = 0; n < 4; ++n)
            Opart[idxp * 64 + n * 16 + li] = accO[n][r];
        if (li == 0)
            *reinterpret_cast<float2*>(mlbuf + idxp * 2) = make_float2(mrun[r], lrun[r]);
    }
}

// ---------------------------------------------------------------------------
// Kernel 2b: merge the two KV-half partials -> Hc bf16 [n][h*64+dv].
// 4 lanes per (h,row) pair; 64 pairs per block; grid 512.
// ---------------------------------------------------------------------------
__global__ __launch_bounds__(256) void combine_kernel(
    const float* __restrict__ Opart, const float* __restrict__ mlbuf,
    unsigned short* __restrict__ Hc)
{
    const int tid = threadIdx.x;
    const int sub = tid & 3;
    const int idx = blockIdx.x * 64 + (tid >> 2);   // 0..32767 = h*2048+row
    const int h = idx >> 11, row = idx & 2047;
    const int HALFSZ = NH * N_TOK;

    float2 a = *reinterpret_cast<const float2*>(mlbuf + (size_t)idx * 2);
    float2 b = *reinterpret_cast<const float2*>(mlbuf + ((size_t)HALFSZ + idx) * 2);
    float M = fmaxf(a.x, b.x);
    float c1 = __expf(a.x - M), c2 = __expf(b.x - M);
    float scale = 0.125f / (a.y * c1 + b.y * c2);
    float s1 = c1 * scale, s2 = c2 * scale;

    const float* O1 = Opart + (size_t)idx * 64 + sub * 16;
    const float* O2 = Opart + ((size_t)HALFSZ + idx) * 64 + sub * 16;
    unsigned short hb[16];
    #pragma unroll
    for (int i = 0; i < 4; ++i) {
        float4 x = *reinterpret_cast<const float4*>(O1 + i * 4);
        float4 y = *reinterpret_cast<const float4*>(O2 + i * 4);
        hb[i * 4 + 0] = f2bf(x.x * s1 + y.x * s2);
        hb[i * 4 + 1] = f2bf(x.y * s1 + y.y * s2);
        hb[i * 4 + 2] = f2bf(x.z * s1 + y.z * s2);
        hb[i * 4 + 3] = f2bf(x.w * s1 + y.w * s2);
    }
    size_t o = (size_t)row * DMODEL + h * 64 + sub * 16;
    *reinterpret_cast<uint4*>(Hc + o)     = *reinterpret_cast<const uint4*>(hb);
    *reinterpret_cast<uint4*>(Hc + o + 8) = *reinterpret_cast<const uint4*>(hb + 8);
}

// ---------------------------------------------------------------------------
// Kernel 3: output projection. out = Hc(bf16 2048x1024) @ Wo(f32 1024x1024) + bo
// ---------------------------------------------------------------------------
__global__ __launch_bounds__(256) void oproj_kernel(
    const unsigned short* __restrict__ Hc,
    const float* __restrict__ Wo,
    const float* __restrict__ bo,
    float* __restrict__ out)
{
    __shared__ alignas(16) unsigned char sA[16384];   // [128][64] bf16 swizzled
    __shared__ alignas(16) unsigned char sB[8192];    // [64 j][64 d] swizzled (Wo^T)

    const int tid = threadIdx.x;
    const int lane = tid & 63;
    const int w = tid >> 6;               // 0..3, rows w*32..+32
    const int g = lane >> 4, li = lane & 15;
    const int row0 = blockIdx.x * 128;
    const int col0 = blockIdx.y * 64;

    f32x4 acc[2][4];
    #pragma unroll
    for (int m = 0; m < 2; ++m)
        #pragma unroll
        for (int n = 0; n < 4; ++n) acc[m][n] = f32x4{0.f, 0.f, 0.f, 0.f};

    for (int kt = 0; kt < DMODEL; kt += 64) {
        __syncthreads();
        // stage A (already bf16): linear 16B chunks
        #pragma unroll
        for (int p = 0; p < 4; ++p) {
            int c = p * 256 + tid;            // 0..1023
            int r = c >> 3, off = (c & 7) * 16;
            *reinterpret_cast<uint4*>(sA + swz(r, off)) =
                *reinterpret_cast<const uint4*>(Hc + (size_t)(row0 + r) * DMODEL + kt + (c & 7) * 8);
        }
        // stage Wo^T tile: Wo[d][j] -> sB[j][d], 4x4 register transpose
        {
            int dq = tid & 15;                // d = dq*4..+3
            int j4 = tid >> 4;                // j = j4*4..+3, 0..15
            int j = j4 * 4;
            const float* src = Wo + (size_t)(kt + dq * 4) * DMODEL + col0 + j;
            float4 r0 = *reinterpret_cast<const float4*>(src);
            float4 r1 = *reinterpret_cast<const float4*>(src + DMODEL);
            float4 r2 = *reinterpret_cast<const float4*>(src + 2 * DMODEL);
            float4 r3 = *reinterpret_cast<const float4*>(src + 3 * DMODEL);
            unsigned short e[16] = {
                f2bf(r0.x), f2bf(r1.x), f2bf(r2.x), f2bf(r3.x),
                f2bf(r0.y), f2bf(r1.y), f2bf(r2.y), f2bf(r3.y),
                f2bf(r0.z), f2bf(r1.z), f2bf(r2.z), f2bf(r3.z),
                f2bf(r0.w), f2bf(r1.w), f2bf(r2.w), f2bf(r3.w)};
            #pragma unroll
            for (int q = 0; q < 4; ++q)
                *reinterpret_cast<uint2*>(sB + swz(j + q, dq * 8)) =
                    *reinterpret_cast<const uint2*>(e + q * 4);
        }
        __syncthreads();

        #pragma unroll
        for (int kk = 0; kk < 2; ++kk) {
            bfrag af[2], bf_[4];
            #pragma unroll
            for (int m = 0; m < 2; ++m)
                af[m] = *reinterpret_cast<const bfrag*>(sA + swz(w * 32 + m * 16 + li, kk * 64 + g * 16));
            #pragma unroll
            for (int n = 0; n < 4; ++n)
                bf_[n] = *reinterpret_cast<const bfrag*>(sB + swz(n * 16 + li, kk * 64 + g * 16));
            #pragma unroll
            for (int m = 0; m < 2; ++m)
                #pragma unroll
                for (int n = 0; n < 4; ++n)
                    acc[m][n] = __builtin_amdgcn_mfma_f32_16x16x32_bf16(af[m], bf_[n], acc[m][n], 0, 0, 0);
        }
    }

    #pragma unroll
    for (int m = 0; m < 2; ++m) {
        #pragma unroll
        for (int n = 0; n < 4; ++n) {
            int colg = col0 + n * 16 + li;
            float bb = bo[colg];
            #pragma unroll
            for (int r = 0; r < 4; ++r) {
                int rowg = row0 + w * 32 + m * 16 + g * 4 + r;
                out[(size_t)rowg * DMODEL + colg] = acc[m][n][r] + bb;
            }
        }
    }
}

extern "C" void kernel_launch(void* const* d_in, const int* in_sizes, int n_in,
                              void* d_out, int out_size, void* d_ws, size_t ws_size,
                              hipStream_t stream) {
    (void)in_sizes; (void)n_in; (void)out_size; (void)ws_size;
    const float* Q  = (const float*)d_in[0];
    const float* K  = (const float*)d_in[1];
    const float* V  = (const float*)d_in[2];
    // d_in[3] = mask (unused by reference forward)
    const float* Wq = (const float*)d_in[4];
    const float* bq = (const float*)d_in[5];
    const float* Wk = (const float*)d_in[6];
    const float* bk = (const float*)d_in[7];
    const float* Wv = (const float*)d_in[8];
    const float* bv = (const float*)d_in[9];
    const float* Wo = (const float*)d_in[10];
    const float* bo = (const float*)d_in[11];
    float* out = (float*)d_out;

    const size_t ASZ = (size_t)N_TOK * DMODEL;   // 2M elems
    const size_t WSZ = (size_t)NH * DK * DMODEL; // 1M elems
    const size_t HSZ = (size_t)NH * N_TOK * DK;  // 2M elems
    unsigned short* p = (unsigned short*)d_ws;
    unsigned short* Ah0 = p; p += ASZ;
    unsigned short* Ah1 = p; p += ASZ;
    unsigned short* Ah2 = p; p += ASZ;
    unsigned short* Al0 = p; p += ASZ;
    unsigned short* Al1 = p; p += ASZ;
    unsigned short* Wth0 = p; p += WSZ;
    unsigned short* Wth1 = p; p += WSZ;
    unsigned short* Wth2 = p; p += WSZ;
    unsigned short* Wtl0 = p; p += WSZ;
    unsigned short* Wtl1 = p; p += WSZ;
    unsigned short* Qhh = p; p += HSZ;
    unsigned short* Qhl = p; p += HSZ;
    unsigned short* Khh = p; p += HSZ;
    unsigned short* Khl = p; p += HSZ;
    unsigned short* Vt  = p; p += HSZ;
    unsigned short* Hc  = p; p += HSZ;

    // attn partials alias the Ah/Al prep region (dead after proj_kernel):
    // Opart 16 MiB + ml 0.5 MiB < 20 MiB region.
    float* Opart = (float*)d_ws;
    float* mlbuf = Opart + (size_t)2 * NH * N_TOK * 64;

    split_act<<<dim3(1024, 3), 256, 0, stream>>>(Q, K, V, Ah0, Ah1, Ah2, Al0, Al1);
    split_w<<<dim3(16, 16, 3), 256, 0, stream>>>(Wq, Wk, Wv, Wth0, Wth1, Wth2, Wtl0, Wtl1);
    proj_kernel<<<dim3(16, 8, 3), 256, 0, stream>>>(
        Ah0, Ah1, Ah2, Al0, Al1, Wth0, Wth1, Wth2, Wtl0, Wtl1,
        bq, bk, bv, Qhh, Qhl, Khh, Khl, Vt);
    attn_kernel<<<dim3(1024), 256, 0, stream>>>(Qhh, Qhl, Khh, Khl, Vt, Opart, mlbuf);
    combine_kernel<<<dim3(512), 256, 0, stream>>>(Opart, mlbuf, Hc);
    oproj_kernel<<<dim3(16, 16), 256, 0, stream>>>(Hc, Wo, bo, out);
}

// Round 5
// 134.838 us; speedup vs baseline: 1.7367x; 1.2527x over previous
//
#include <hip/hip_runtime.h>

#define N_TOK 2048
#define DMODEL 1024
#define NH 16
#define DK 64

typedef __attribute__((ext_vector_type(8))) short bfrag;   // 8 bf16 = one MFMA A/B operand
typedef __attribute__((ext_vector_type(4))) float f32x4;   // MFMA C/D

__device__ __forceinline__ unsigned short f2bf(float f) {
    unsigned u = __builtin_bit_cast(unsigned, f);
    u += 0x7FFFu + ((u >> 16) & 1u);          // round-to-nearest-even
    return (unsigned short)(u >> 16);
}
__device__ __forceinline__ float bf2f(unsigned short u) {
    unsigned x = ((unsigned)u) << 16;
    return __builtin_bit_cast(float, x);
}
// packed f32x2 -> bf16x2 (RNE), single HW instruction
__device__ __forceinline__ unsigned cvtpk(float lo, float hi) {
    unsigned r;
    asm volatile("v_cvt_pk_bf16_f32 %0, %1, %2" : "=v"(r) : "v"(lo), "v"(hi));
    return r;
}

// swizzled byte offset inside a [rows][64 bf16] LDS tile (128 B rows).
__device__ __forceinline__ int swz(int row, int b) {
    return row * 128 + (b ^ ((row & 7) << 4));
}

// async global->LDS 16B: LDS dest wave-uniform base (+lane*16 by HW);
// global src per-lane (carries the inverse swizzle).
__device__ __forceinline__ void gload16(const void* g, void* l) {
    __builtin_amdgcn_global_load_lds(
        (__attribute__((address_space(1))) void*)g,
        (__attribute__((address_space(3))) void*)l,
        16, 0, 0);
}

// ---------------------------------------------------------------------------
// Prep 1: split activations Q,K,V (f32 [2048][1024]) -> bf16 hi (+lo for Q,K).
// ---------------------------------------------------------------------------
__global__ __launch_bounds__(256) void split_act(
    const float* __restrict__ Qin, const float* __restrict__ Kin, const float* __restrict__ Vin,
    unsigned short* __restrict__ Ah0, unsigned short* __restrict__ Ah1, unsigned short* __restrict__ Ah2,
    unsigned short* __restrict__ Al0, unsigned short* __restrict__ Al1)
{
    const int z = blockIdx.y;
    const float* src = (z == 0) ? Qin : (z == 1) ? Kin : Vin;
    unsigned short* dh = (z == 0) ? Ah0 : (z == 1) ? Ah1 : Ah2;
    unsigned short* dl = (z == 0) ? Al0 : (z == 1) ? Al1 : nullptr;

    size_t base = ((size_t)blockIdx.x * 256 + threadIdx.x) * 8;
    float4 a = *reinterpret_cast<const float4*>(src + base);
    float4 b = *reinterpret_cast<const float4*>(src + base + 4);
    float f[8] = {a.x, a.y, a.z, a.w, b.x, b.y, b.z, b.w};
    unsigned short hb[8], lb[8];
    #pragma unroll
    for (int i = 0; i < 8; ++i) {
        hb[i] = f2bf(f[i]);
        lb[i] = f2bf(f[i] - bf2f(hb[i]));
    }
    *reinterpret_cast<uint4*>(dh + base) = *reinterpret_cast<const uint4*>(hb);
    if (z < 2)
        *reinterpret_cast<uint4*>(dl + base) = *reinterpret_cast<const uint4*>(lb);
}

// ---------------------------------------------------------------------------
// Prep 2: W[h][d][k] (f32) -> W^T[j=h*64+k][d] bf16 hi (+lo for Q,K).
// ---------------------------------------------------------------------------
__global__ __launch_bounds__(256) void split_w(
    const float* __restrict__ Wq_, const float* __restrict__ Wk_, const float* __restrict__ Wv_,
    unsigned short* __restrict__ Wth0, unsigned short* __restrict__ Wth1, unsigned short* __restrict__ Wth2,
    unsigned short* __restrict__ Wtl0, unsigned short* __restrict__ Wtl1)
{
    const int z = blockIdx.z;
    const float* W = (z == 0) ? Wq_ : (z == 1) ? Wk_ : Wv_;
    unsigned short* oh = (z == 0) ? Wth0 : (z == 1) ? Wth1 : Wth2;
    unsigned short* ol = (z == 0) ? Wtl0 : (z == 1) ? Wtl1 : nullptr;
    const int h = blockIdx.y, dt = blockIdx.x;
    const int tid = threadIdx.x;

    __shared__ float lds[64][65];

    {   // load 64(d) x 64(k) f32 tile, coalesced
        int rr = tid >> 2, c4 = (tid & 3) * 16;
        const float* src = W + ((size_t)h * DMODEL + dt * 64 + rr) * DK + c4;
        #pragma unroll
        for (int i = 0; i < 4; ++i) {
            float4 v = *reinterpret_cast<const float4*>(src + i * 4);
            lds[rr][c4 + i * 4 + 0] = v.x;
            lds[rr][c4 + i * 4 + 1] = v.y;
            lds[rr][c4 + i * 4 + 2] = v.z;
            lds[rr][c4 + i * 4 + 3] = v.w;
        }
    }
    __syncthreads();
    {   // write transposed: row k, 16 d-values per thread
        int kk_ = tid >> 2, d4 = (tid & 3) * 16;
        unsigned short hb[16], lb[16];
        #pragma unroll
        for (int i = 0; i < 16; ++i) {
            float v = lds[d4 + i][kk_];
            hb[i] = f2bf(v);
            lb[i] = f2bf(v - bf2f(hb[i]));
        }
        size_t o = (size_t)(h * 64 + kk_) * DMODEL + dt * 64 + d4;
        *reinterpret_cast<uint4*>(oh + o)     = *reinterpret_cast<const uint4*>(hb);
        *reinterpret_cast<uint4*>(oh + o + 8) = *reinterpret_cast<const uint4*>(hb + 8);
        if (z < 2) {
            *reinterpret_cast<uint4*>(ol + o)     = *reinterpret_cast<const uint4*>(lb);
            *reinterpret_cast<uint4*>(ol + o + 8) = *reinterpret_cast<const uint4*>(lb + 8);
        }
    }
}

// ---------------------------------------------------------------------------
// Prep 3: Wo[d][j] (f32 1024x1024) -> WoT[j][d] bf16 hi.
// ---------------------------------------------------------------------------
__global__ __launch_bounds__(256) void split_wo(
    const float* __restrict__ Wo, unsigned short* __restrict__ WoT)
{
    const int dt = blockIdx.x, jt = blockIdx.y;
    const int tid = threadIdx.x;
    __shared__ float lds[64][65];

    {
        int rr = tid >> 2, c4 = (tid & 3) * 16;
        const float* src = Wo + (size_t)(dt * 64 + rr) * DMODEL + jt * 64 + c4;
        #pragma unroll
        for (int i = 0; i < 4; ++i) {
            float4 v = *reinterpret_cast<const float4*>(src + i * 4);
            lds[rr][c4 + i * 4 + 0] = v.x;
            lds[rr][c4 + i * 4 + 1] = v.y;
            lds[rr][c4 + i * 4 + 2] = v.z;
            lds[rr][c4 + i * 4 + 3] = v.w;
        }
    }
    __syncthreads();
    {
        int jj = tid >> 2, d4 = (tid & 3) * 16;
        unsigned short hb[16];
        #pragma unroll
        for (int i = 0; i < 16; ++i) hb[i] = f2bf(lds[d4 + i][jj]);
        size_t o = (size_t)(jt * 64 + jj) * DMODEL + dt * 64 + d4;
        *reinterpret_cast<uint4*>(WoT + o)     = *reinterpret_cast<const uint4*>(hb);
        *reinterpret_cast<uint4*>(WoT + o + 8) = *reinterpret_cast<const uint4*>(hb + 8);
    }
}

// ---------------------------------------------------------------------------
// Kernel 1: per-head input projections, staging via global_load_lds.
// z=0,1 (Q,K): 3-term split-bf16 MFMA -> hi/lo bf16 head-major [h][n][k].
// z=2   (V) : 1-term MFMA -> bf16 TRANSPOSED per head: Vt[h][dv][token].
// ---------------------------------------------------------------------------
__global__ __launch_bounds__(256) void proj_kernel(
    const unsigned short* __restrict__ Ah0, const unsigned short* __restrict__ Ah1, const unsigned short* __restrict__ Ah2,
    const unsigned short* __restrict__ Al0, const unsigned short* __restrict__ Al1,
    const unsigned short* __restrict__ Wth0, const unsigned short* __restrict__ Wth1, const unsigned short* __restrict__ Wth2,
    const unsigned short* __restrict__ Wtl0, const unsigned short* __restrict__ Wtl1,
    const float* __restrict__ bq_, const float* __restrict__ bk_, const float* __restrict__ bv_,
    unsigned short* __restrict__ Qhh, unsigned short* __restrict__ Qhl,
    unsigned short* __restrict__ Khh, unsigned short* __restrict__ Khl,
    unsigned short* __restrict__ Vt)
{
    const int z = blockIdx.z;
    const unsigned short* Ah = (z == 0) ? Ah0 : (z == 1) ? Ah1 : Ah2;
    const unsigned short* Al = (z == 0) ? Al0 : Al1;
    const unsigned short* Bh = (z == 0) ? Wth0 : (z == 1) ? Wth1 : Wth2;
    const unsigned short* Bl = (z == 0) ? Wtl0 : Wtl1;
    const float* bias = (z == 0) ? bq_ : (z == 1) ? bk_ : bv_;

    __shared__ alignas(16) unsigned char sAh[16384];   // [128 rows][64 bf16] swizzled, hi
    __shared__ alignas(16) unsigned char sAl[16384];   // lo
    __shared__ alignas(16) unsigned char sBh[16384];   // [128 j][64 d] swizzled, hi
    __shared__ alignas(16) unsigned char sBl[16384];   // lo

    const int tid = threadIdx.x;
    const int lane = tid & 63;
    const int w = tid >> 6;               // 0..3
    const int wm = w >> 1, wn = w & 1;    // 2x2 wave grid
    const int g = lane >> 4, li = lane & 15;

    const int row0 = blockIdx.x * 128;    // token rows
    const int col0 = blockIdx.y * 128;    // output cols (h*64+k)

    f32x4 acc[4][4];
    #pragma unroll
    for (int m = 0; m < 4; ++m)
        #pragma unroll
        for (int n = 0; n < 4; ++n) acc[m][n] = f32x4{0.f, 0.f, 0.f, 0.f};

    for (int kt = 0; kt < DMODEL; kt += 64) {
        __syncthreads();
        #pragma unroll
        for (int p = 0; p < 4; ++p) {
            int chunk = p * 256 + tid;           // 16B chunk id, 0..1023
            int r = chunk >> 3, cc = chunk & 7;  // row, col-chunk
            int cs = (cc * 8) ^ ((r & 7) << 3);  // pre-swizzled short offset
            int ldso = (p * 256 + w * 64) * 16;  // wave-uniform LDS base
            gload16(Ah + (size_t)(row0 + r) * DMODEL + kt + cs, sAh + ldso);
            gload16(Bh + (size_t)(col0 + r) * DMODEL + kt + cs, sBh + ldso);
            if (z < 2) {
                gload16(Al + (size_t)(row0 + r) * DMODEL + kt + cs, sAl + ldso);
                gload16(Bl + (size_t)(col0 + r) * DMODEL + kt + cs, sBl + ldso);
            }
        }
        __syncthreads();

        if (z < 2) {
            #pragma unroll
            for (int kk = 0; kk < 2; ++kk) {
                bfrag afh[4], afl[4], bfh[4], bfl[4];
                #pragma unroll
                for (int m = 0; m < 4; ++m) {
                    afh[m] = *reinterpret_cast<const bfrag*>(sAh + swz(wm * 64 + m * 16 + li, kk * 64 + g * 16));
                    afl[m] = *reinterpret_cast<const bfrag*>(sAl + swz(wm * 64 + m * 16 + li, kk * 64 + g * 16));
                }
                #pragma unroll
                for (int n = 0; n < 4; ++n) {
                    bfh[n] = *reinterpret_cast<const bfrag*>(sBh + swz(wn * 64 + n * 16 + li, kk * 64 + g * 16));
                    bfl[n] = *reinterpret_cast<const bfrag*>(sBl + swz(wn * 64 + n * 16 + li, kk * 64 + g * 16));
                }
                #pragma unroll
                for (int m = 0; m < 4; ++m)
                    #pragma unroll
                    for (int n = 0; n < 4; ++n) {
                        acc[m][n] = __builtin_amdgcn_mfma_f32_16x16x32_bf16(afh[m], bfh[n], acc[m][n], 0, 0, 0);
                        acc[m][n] = __builtin_amdgcn_mfma_f32_16x16x32_bf16(afl[m], bfh[n], acc[m][n], 0, 0, 0);
                        acc[m][n] = __builtin_amdgcn_mfma_f32_16x16x32_bf16(afh[m], bfl[n], acc[m][n], 0, 0, 0);
                    }
            }
        } else {
            #pragma unroll
            for (int kk = 0; kk < 2; ++kk) {
                bfrag afh[4], bfh[4];
                #pragma unroll
                for (int m = 0; m < 4; ++m)
                    afh[m] = *reinterpret_cast<const bfrag*>(sAh + swz(wm * 64 + m * 16 + li, kk * 64 + g * 16));
                #pragma unroll
                for (int n = 0; n < 4; ++n)
                    bfh[n] = *reinterpret_cast<const bfrag*>(sBh + swz(wn * 64 + n * 16 + li, kk * 64 + g * 16));
                #pragma unroll
                for (int m = 0; m < 4; ++m)
                    #pragma unroll
                    for (int n = 0; n < 4; ++n)
                        acc[m][n] = __builtin_amdgcn_mfma_f32_16x16x32_bf16(afh[m], bfh[n], acc[m][n], 0, 0, 0);
            }
        }
    }

    // epilogue: +bias; Q,K -> hi/lo bf16 head-major; V -> bf16 transposed
    #pragma unroll
    for (int m = 0; m < 4; ++m) {
        #pragma unroll
        for (int n = 0; n < 4; ++n) {
            int colg = col0 + wn * 64 + n * 16 + li;
            float bb = bias[colg];
            int hh = colg >> 6, k = colg & 63;
            int rowb = row0 + wm * 64 + m * 16 + g * 4;
            if (z == 2) {
                unsigned short vb4[4];
                #pragma unroll
                for (int r = 0; r < 4; ++r) vb4[r] = f2bf(acc[m][n][r] + bb);
                *reinterpret_cast<uint2*>(Vt + ((size_t)hh * DK + k) * N_TOK + rowb) =
                    *reinterpret_cast<const uint2*>(vb4);
            } else {
                #pragma unroll
                for (int r = 0; r < 4; ++r) {
                    size_t o = ((size_t)hh * N_TOK + rowb + r) * DK + k;
                    float val = acc[m][n][r] + bb;
                    unsigned short hb = f2bf(val);
                    unsigned short lb = f2bf(val - bf2f(hb));
                    if (z == 0) { Qhh[o] = hb; Qhl[o] = lb; }
                    else        { Khh[o] = hb; Khl[o] = lb; }
                }
            }
        }
    }
}

// ---------------------------------------------------------------------------
// Kernel 2: flash attention, KV-split, SWAPPED QK^T (S^T = K Q^T) so each
// lane owns one q-row: row-max/sum are in-lane + 2 shfl; P packed via
// v_cvt_pk_bf16_f32 and stored with 4x ds_write_b64.
// ---------------------------------------------------------------------------
__global__ __launch_bounds__(256) void attn_kernel(
    const unsigned short* __restrict__ Qhh, const unsigned short* __restrict__ Qhl,
    const unsigned short* __restrict__ Khh, const unsigned short* __restrict__ Khl,
    const unsigned short* __restrict__ Vt,
    float* __restrict__ Opart, float* __restrict__ mlbuf)
{
    __shared__ alignas(16) unsigned char sKh[8192];   // [64 key][64 k] swizzled, hi
    __shared__ alignas(16) unsigned char sKl[8192];   // lo
    __shared__ alignas(16) unsigned char sV[8192];    // [64 dv][64 key] swizzled
    __shared__ alignas(16) unsigned char sP[8192];    // per-wave 16x64 P tiles

    // XCD swizzle: 128-block contiguous chunks per XCD
    const int bid = blockIdx.x;                  // 0..1023
    const int orig = (bid & 7) * 128 + (bid >> 3);
    const int h    = orig >> 6;
    const int half = (orig >> 5) & 1;
    const int qt   = orig & 31;

    const int tid = threadIdx.x;
    const int lane = tid & 63;
    const int w = tid >> 6;               // 0..3
    const int g = lane >> 4, li = lane & 15;
    const int qrow0 = qt * 64 + w * 16;

    const unsigned short* QbH = Qhh + (size_t)h * N_TOK * DK;
    const unsigned short* QbL = Qhl + (size_t)h * N_TOK * DK;
    const unsigned short* KbH = Khh + (size_t)h * N_TOK * DK;
    const unsigned short* KbL = Khl + (size_t)h * N_TOK * DK;
    const unsigned short* Vtb = Vt  + (size_t)h * DK * N_TOK;
    unsigned char* sPw = sP + w * 2048;

    // Q fragments (hi/lo): lane li covers q-row qrow0+li, k-chunk kk*32+g*8
    bfrag aqh[2], aql[2];
    #pragma unroll
    for (int kk = 0; kk < 2; ++kk) {
        size_t o = (size_t)(qrow0 + li) * DK + kk * 32 + g * 8;
        aqh[kk] = *reinterpret_cast<const bfrag*>(QbH + o);
        aql[kk] = *reinterpret_cast<const bfrag*>(QbL + o);
    }

    f32x4 accO[4];
    #pragma unroll
    for (int n = 0; n < 4; ++n) accO[n] = f32x4{0.f, 0.f, 0.f, 0.f};
    float mrun = -3.0e38f, lrun = 0.f;    // per-lane: q-row li (replicated over g)

    for (int tt = 0; tt < 16; ++tt) {
        const int t = half * 1024 + tt * 64;
        __syncthreads();                       // previous tile fully consumed
        #pragma unroll
        for (int p = 0; p < 2; ++p) {
            int chunk = p * 256 + w * 64 + lane;
            int r = chunk >> 3;
            int cs = ((chunk & 7) * 8) ^ ((r & 7) << 3);
            int ldso = (p * 256 + w * 64) * 16;
            gload16(KbH + (size_t)(t + r) * DK + cs, sKh + ldso);
            gload16(KbL + (size_t)(t + r) * DK + cs, sKl + ldso);
            gload16(Vtb + (size_t)r * N_TOK + t + cs, sV + ldso);
        }
        __syncthreads();

        // S^T = K Q^T: s[n] row = key n*16+g*4+r, col = q-row li
        f32x4 s[4];
        #pragma unroll
        for (int n = 0; n < 4; ++n) s[n] = f32x4{0.f, 0.f, 0.f, 0.f};
        #pragma unroll
        for (int kk = 0; kk < 2; ++kk) {
            #pragma unroll
            for (int n = 0; n < 4; ++n) {
                bfrag bkh = *reinterpret_cast<const bfrag*>(sKh + swz(n * 16 + li, kk * 64 + g * 16));
                bfrag bkl = *reinterpret_cast<const bfrag*>(sKl + swz(n * 16 + li, kk * 64 + g * 16));
                s[n] = __builtin_amdgcn_mfma_f32_16x16x32_bf16(bkh, aqh[kk], s[n], 0, 0, 0);
                s[n] = __builtin_amdgcn_mfma_f32_16x16x32_bf16(bkh, aql[kk], s[n], 0, 0, 0);
                s[n] = __builtin_amdgcn_mfma_f32_16x16x32_bf16(bkl, aqh[kk], s[n], 0, 0, 0);
            }
        }

        // online softmax, in-lane (lane owns q-row li, 16 keys)
        float a0 = fmaxf(fmaxf(s[0][0], s[0][1]), fmaxf(s[0][2], s[0][3]));
        float a1 = fmaxf(fmaxf(s[1][0], s[1][1]), fmaxf(s[1][2], s[1][3]));
        float a2 = fmaxf(fmaxf(s[2][0], s[2][1]), fmaxf(s[2][2], s[2][3]));
        float a3 = fmaxf(fmaxf(s[3][0], s[3][1]), fmaxf(s[3][2], s[3][3]));
        float tm = fmaxf(fmaxf(a0, a1), fmaxf(a2, a3));
        tm = fmaxf(tm, __shfl_xor(tm, 16));
        tm = fmaxf(tm, __shfl_xor(tm, 32));
        float nm = fmaxf(mrun, tm);
        float sc = __expf(mrun - nm);
        mrun = nm;
        lrun *= sc;

        // P = exp(S - m): pack to bf16 pairs, store 8B per n-block; sum in-lane
        float ps = 0.f;
        #pragma unroll
        for (int n = 0; n < 4; ++n) {
            float p0 = __expf(s[n][0] - nm);
            float p1 = __expf(s[n][1] - nm);
            float p2 = __expf(s[n][2] - nm);
            float p3 = __expf(s[n][3] - nm);
            ps += (p0 + p1) + (p2 + p3);
            uint2 pw = make_uint2(cvtpk(p0, p1), cvtpk(p2, p3));
            *reinterpret_cast<uint2*>(sPw + swz(li, (n * 16 + g * 4) * 2)) = pw;
        }
        ps += __shfl_xor(ps, 16);
        ps += __shfl_xor(ps, 32);
        lrun += ps;

        // rescale accO (rows g*4+r) by sc of those rows
        float scr[4];
        #pragma unroll
        for (int r = 0; r < 4; ++r) scr[r] = __shfl(sc, g * 4 + r);
        #pragma unroll
        for (int n = 0; n < 4; ++n)
            #pragma unroll
            for (int r = 0; r < 4; ++r)
                accO[n][r] *= scr[r];

        // O += P @ V_tile (P re-read from wave-private LDS in A-frag layout)
        #pragma unroll
        for (int kk = 0; kk < 2; ++kk) {
            bfrag pa = *reinterpret_cast<const bfrag*>(sPw + swz(li, kk * 64 + g * 16));
            #pragma unroll
            for (int n = 0; n < 4; ++n) {
                bfrag vb = *reinterpret_cast<const bfrag*>(sV + swz(n * 16 + li, kk * 64 + g * 16));
                accO[n] = __builtin_amdgcn_mfma_f32_16x16x32_bf16(pa, vb, accO[n], 0, 0, 0);
            }
        }
    }

    // epilogue: unnormalized partial O (f32) + per-row (m,l)
    const size_t pbase = (size_t)half * NH * N_TOK;
    #pragma unroll
    for (int r = 0; r < 4; ++r) {
        int row = qrow0 + g * 4 + r;
        size_t idxp = pbase + (size_t)h * N_TOK + row;
        #pragma unroll
        for (int n = 0; n < 4; ++n)
            Opart[idxp * 64 + n * 16 + li] = accO[n][r];
    }
    if (lane < 16) {   // g==0 lanes hold (m,l) for q-row li
        size_t idxp = pbase + (size_t)h * N_TOK + qrow0 + lane;
        *reinterpret_cast<float2*>(mlbuf + idxp * 2) = make_float2(mrun, lrun);
    }
}

// ---------------------------------------------------------------------------
// Kernel 2b: merge the two KV-half partials -> Hc bf16 [n][h*64+dv].
// ---------------------------------------------------------------------------
__global__ __launch_bounds__(256) void combine_kernel(
    const float* __restrict__ Opart, const float* __restrict__ mlbuf,
    unsigned short* __restrict__ Hc)
{
    const int tid = threadIdx.x;
    const int sub = tid & 3;
    const int idx = blockIdx.x * 64 + (tid >> 2);   // h*2048+row
    const int h = idx >> 11, row = idx & 2047;
    const int HALFSZ = NH * N_TOK;

    float2 a = *reinterpret_cast<const float2*>(mlbuf + (size_t)idx * 2);
    float2 b = *reinterpret_cast<const float2*>(mlbuf + ((size_t)HALFSZ + idx) * 2);
    float M = fmaxf(a.x, b.x);
    float c1 = __expf(a.x - M), c2 = __expf(b.x - M);
    float scale = 0.125f / (a.y * c1 + b.y * c2);
    float s1 = c1 * scale, s2 = c2 * scale;

    const float* O1 = Opart + (size_t)idx * 64 + sub * 16;
    const float* O2 = Opart + ((size_t)HALFSZ + idx) * 64 + sub * 16;
    unsigned short hb[16];
    #pragma unroll
    for (int i = 0; i < 4; ++i) {
        float4 x = *reinterpret_cast<const float4*>(O1 + i * 4);
        float4 y = *reinterpret_cast<const float4*>(O2 + i * 4);
        hb[i * 4 + 0] = f2bf(x.x * s1 + y.x * s2);
        hb[i * 4 + 1] = f2bf(x.y * s1 + y.y * s2);
        hb[i * 4 + 2] = f2bf(x.z * s1 + y.z * s2);
        hb[i * 4 + 3] = f2bf(x.w * s1 + y.w * s2);
    }
    size_t o = (size_t)row * DMODEL + h * 64 + sub * 16;
    *reinterpret_cast<uint4*>(Hc + o)     = *reinterpret_cast<const uint4*>(hb);
    *reinterpret_cast<uint4*>(Hc + o + 8) = *reinterpret_cast<const uint4*>(hb + 8);
}

// ---------------------------------------------------------------------------
// Kernel 3: output projection, all-bf16 via pre-transposed WoT.
// Tile 128x128, BK=64, 4 waves (2x2), gload_lds staging. f32 out + bo.
// ---------------------------------------------------------------------------
__global__ __launch_bounds__(256) void oproj_kernel(
    const unsigned short* __restrict__ Hc,
    const unsigned short* __restrict__ WoT,
    const float* __restrict__ bo,
    float* __restrict__ out)
{
    __shared__ alignas(16) unsigned char sA[16384];   // [128][64] bf16 swizzled
    __shared__ alignas(16) unsigned char sB[16384];   // [128 j][64 d] swizzled

    const int tid = threadIdx.x;
    const int lane = tid & 63;
    const int w = tid >> 6;
    const int wm = w >> 1, wn = w & 1;
    const int g = lane >> 4, li = lane & 15;
    const int row0 = blockIdx.x * 128;
    const int col0 = blockIdx.y * 128;

    f32x4 acc[4][4];
    #pragma unroll
    for (int m = 0; m < 4; ++m)
        #pragma unroll
        for (int n = 0; n < 4; ++n) acc[m][n] = f32x4{0.f, 0.f, 0.f, 0.f};

    for (int kt = 0; kt < DMODEL; kt += 64) {
        __syncthreads();
        #pragma unroll
        for (int p = 0; p < 4; ++p) {
            int chunk = p * 256 + tid;
            int r = chunk >> 3, cc = chunk & 7;
            int cs = (cc * 8) ^ ((r & 7) << 3);
            int ldso = (p * 256 + w * 64) * 16;
            gload16(Hc  + (size_t)(row0 + r) * DMODEL + kt + cs, sA + ldso);
            gload16(WoT + (size_t)(col0 + r) * DMODEL + kt + cs, sB + ldso);
        }
        __syncthreads();

        #pragma unroll
        for (int kk = 0; kk < 2; ++kk) {
            bfrag af[4], bf_[4];
            #pragma unroll
            for (int m = 0; m < 4; ++m)
                af[m] = *reinterpret_cast<const bfrag*>(sA + swz(wm * 64 + m * 16 + li, kk * 64 + g * 16));
            #pragma unroll
            for (int n = 0; n < 4; ++n)
                bf_[n] = *reinterpret_cast<const bfrag*>(sB + swz(wn * 64 + n * 16 + li, kk * 64 + g * 16));
            #pragma unroll
            for (int m = 0; m < 4; ++m)
                #pragma unroll
                for (int n = 0; n < 4; ++n)
                    acc[m][n] = __builtin_amdgcn_mfma_f32_16x16x32_bf16(af[m], bf_[n], acc[m][n], 0, 0, 0);
        }
    }

    #pragma unroll
    for (int m = 0; m < 4; ++m) {
        #pragma unroll
        for (int n = 0; n < 4; ++n) {
            int colg = col0 + wn * 64 + n * 16 + li;
            float bb = bo[colg];
            #pragma unroll
            for (int r = 0; r < 4; ++r) {
                int rowg = row0 + wm * 64 + m * 16 + g * 4 + r;
                out[(size_t)rowg * DMODEL + colg] = acc[m][n][r] + bb;
            }
        }
    }
}

extern "C" void kernel_launch(void* const* d_in, const int* in_sizes, int n_in,
                              void* d_out, int out_size, void* d_ws, size_t ws_size,
                              hipStream_t stream) {
    (void)in_sizes; (void)n_in; (void)out_size; (void)ws_size;
    const float* Q  = (const float*)d_in[0];
    const float* K  = (const float*)d_in[1];
    const float* V  = (const float*)d_in[2];
    // d_in[3] = mask (unused by reference forward)
    const float* Wq = (const float*)d_in[4];
    const float* bq = (const float*)d_in[5];
    const float* Wk = (const float*)d_in[6];
    const float* bk = (const float*)d_in[7];
    const float* Wv = (const float*)d_in[8];
    const float* bv = (const float*)d_in[9];
    const float* Wo = (const float*)d_in[10];
    const float* bo = (const float*)d_in[11];
    float* out = (float*)d_out;

    const size_t ASZ = (size_t)N_TOK * DMODEL;   // 2M elems
    const size_t WSZ = (size_t)NH * DK * DMODEL; // 1M elems
    const size_t HSZ = (size_t)NH * N_TOK * DK;  // 2M elems
    unsigned short* p = (unsigned short*)d_ws;
    unsigned short* Ah0 = p; p += ASZ;
    unsigned short* Ah1 = p; p += ASZ;
    unsigned short* Ah2 = p; p += ASZ;
    unsigned short* Al0 = p; p += ASZ;
    unsigned short* Al1 = p; p += ASZ;
    unsigned short* Wth0 = p; p += WSZ;
    unsigned short* Wth1 = p; p += WSZ;
    unsigned short* Wth2 = p; p += WSZ;
    unsigned short* Wtl0 = p; p += WSZ;
    unsigned short* Wtl1 = p; p += WSZ;
    unsigned short* Qhh = p; p += HSZ;
    unsigned short* Qhl = p; p += HSZ;
    unsigned short* Khh = p; p += HSZ;
    unsigned short* Khl = p; p += HSZ;
    unsigned short* Vt  = p; p += HSZ;
    unsigned short* Hc  = p; p += HSZ;
    unsigned short* WoT = p; p += ASZ / 2;       // 1M elems (1024x1024 bf16)

    // attn partials alias the Ah/Al prep region (dead after proj_kernel):
    float* Opart = (float*)d_ws;
    float* mlbuf = Opart + (size_t)2 * NH * N_TOK * 64;

    split_act<<<dim3(1024, 3), 256, 0, stream>>>(Q, K, V, Ah0, Ah1, Ah2, Al0, Al1);
    split_w<<<dim3(16, 16, 3), 256, 0, stream>>>(Wq, Wk, Wv, Wth0, Wth1, Wth2, Wtl0, Wtl1);
    split_wo<<<dim3(16, 16), 256, 0, stream>>>(Wo, WoT);
    proj_kernel<<<dim3(16, 8, 3), 256, 0, stream>>>(
        Ah0, Ah1, Ah2, Al0, Al1, Wth0, Wth1, Wth2, Wtl0, Wtl1,
        bq, bk, bv, Qhh, Qhl, Khh, Khl, Vt);
    attn_kernel<<<dim3(1024), 256, 0, stream>>>(Qhh, Qhl, Khh, Khl, Vt, Opart, mlbuf);
    combine_kernel<<<dim3(512), 256, 0, stream>>>(Opart, mlbuf, Hc);
    oproj_kernel<<<dim3(16, 8), 256, 0, stream>>>(Hc, WoT, bo, out);
}

// Round 6
// 128.448 us; speedup vs baseline: 1.8231x; 1.0498x over previous
//
#include <hip/hip_runtime.h>

#define N_TOK 2048
#define DMODEL 1024
#define NH 16
#define DK 64

typedef __attribute__((ext_vector_type(8))) short bfrag;   // 8 bf16 = one MFMA A/B operand
typedef __attribute__((ext_vector_type(4))) float f32x4;   // 16x16 MFMA C/D
typedef __attribute__((ext_vector_type(16))) float f32x16; // 32x32 MFMA C/D
typedef __attribute__((ext_vector_type(4))) unsigned u32x4;

__device__ __forceinline__ unsigned short f2bf(float f) {
    unsigned u = __builtin_bit_cast(unsigned, f);
    u += 0x7FFFu + ((u >> 16) & 1u);          // round-to-nearest-even
    return (unsigned short)(u >> 16);
}
__device__ __forceinline__ float bf2f(unsigned short u) {
    unsigned x = ((unsigned)u) << 16;
    return __builtin_bit_cast(float, x);
}
// packed f32x2 -> bf16x2 (RNE), single HW instruction
__device__ __forceinline__ unsigned cvtpk(float lo, float hi) {
    unsigned r;
    asm volatile("v_cvt_pk_bf16_f32 %0, %1, %2" : "=v"(r) : "v"(lo), "v"(hi));
    return r;
}

// swizzled byte offset inside a [rows][64 bf16] LDS tile (128 B rows).
__device__ __forceinline__ int swz(int row, int b) {
    return row * 128 + (b ^ ((row & 7) << 4));
}

// async global->LDS 16B: LDS dest wave-uniform base (+lane*16 by HW);
// global src per-lane (carries the inverse swizzle).
__device__ __forceinline__ void gload16(const void* g, void* l) {
    __builtin_amdgcn_global_load_lds(
        (__attribute__((address_space(1))) void*)g,
        (__attribute__((address_space(3))) void*)l,
        16, 0, 0);
}

// ---------------------------------------------------------------------------
// Prep 1: split activations Q,K,V (f32 [2048][1024]) -> bf16 hi (+lo for Q,K).
// ---------------------------------------------------------------------------
__global__ __launch_bounds__(256) void split_act(
    const float* __restrict__ Qin, const float* __restrict__ Kin, const float* __restrict__ Vin,
    unsigned short* __restrict__ Ah0, unsigned short* __restrict__ Ah1, unsigned short* __restrict__ Ah2,
    unsigned short* __restrict__ Al0, unsigned short* __restrict__ Al1)
{
    const int z = blockIdx.y;
    const float* src = (z == 0) ? Qin : (z == 1) ? Kin : Vin;
    unsigned short* dh = (z == 0) ? Ah0 : (z == 1) ? Ah1 : Ah2;
    unsigned short* dl = (z == 0) ? Al0 : (z == 1) ? Al1 : nullptr;

    size_t base = ((size_t)blockIdx.x * 256 + threadIdx.x) * 8;
    float4 a = *reinterpret_cast<const float4*>(src + base);
    float4 b = *reinterpret_cast<const float4*>(src + base + 4);
    float f[8] = {a.x, a.y, a.z, a.w, b.x, b.y, b.z, b.w};
    unsigned short hb[8], lb[8];
    #pragma unroll
    for (int i = 0; i < 8; ++i) {
        hb[i] = f2bf(f[i]);
        lb[i] = f2bf(f[i] - bf2f(hb[i]));
    }
    *reinterpret_cast<uint4*>(dh + base) = *reinterpret_cast<const uint4*>(hb);
    if (z < 2)
        *reinterpret_cast<uint4*>(dl + base) = *reinterpret_cast<const uint4*>(lb);
}

// ---------------------------------------------------------------------------
// Prep 2: W[h][d][k] (f32) -> W^T[j=h*64+k][d] bf16 hi (+lo for Q,K).
// ---------------------------------------------------------------------------
__global__ __launch_bounds__(256) void split_w(
    const float* __restrict__ Wq_, const float* __restrict__ Wk_, const float* __restrict__ Wv_,
    unsigned short* __restrict__ Wth0, unsigned short* __restrict__ Wth1, unsigned short* __restrict__ Wth2,
    unsigned short* __restrict__ Wtl0, unsigned short* __restrict__ Wtl1)
{
    const int z = blockIdx.z;
    const float* W = (z == 0) ? Wq_ : (z == 1) ? Wk_ : Wv_;
    unsigned short* oh = (z == 0) ? Wth0 : (z == 1) ? Wth1 : Wth2;
    unsigned short* ol = (z == 0) ? Wtl0 : (z == 1) ? Wtl1 : nullptr;
    const int h = blockIdx.y, dt = blockIdx.x;
    const int tid = threadIdx.x;

    __shared__ float lds[64][65];

    {   // load 64(d) x 64(k) f32 tile, coalesced
        int rr = tid >> 2, c4 = (tid & 3) * 16;
        const float* src = W + ((size_t)h * DMODEL + dt * 64 + rr) * DK + c4;
        #pragma unroll
        for (int i = 0; i < 4; ++i) {
            float4 v = *reinterpret_cast<const float4*>(src + i * 4);
            lds[rr][c4 + i * 4 + 0] = v.x;
            lds[rr][c4 + i * 4 + 1] = v.y;
            lds[rr][c4 + i * 4 + 2] = v.z;
            lds[rr][c4 + i * 4 + 3] = v.w;
        }
    }
    __syncthreads();
    {   // write transposed: row k, 16 d-values per thread
        int kk_ = tid >> 2, d4 = (tid & 3) * 16;
        unsigned short hb[16], lb[16];
        #pragma unroll
        for (int i = 0; i < 16; ++i) {
            float v = lds[d4 + i][kk_];
            hb[i] = f2bf(v);
            lb[i] = f2bf(v - bf2f(hb[i]));
        }
        size_t o = (size_t)(h * 64 + kk_) * DMODEL + dt * 64 + d4;
        *reinterpret_cast<uint4*>(oh + o)     = *reinterpret_cast<const uint4*>(hb);
        *reinterpret_cast<uint4*>(oh + o + 8) = *reinterpret_cast<const uint4*>(hb + 8);
        if (z < 2) {
            *reinterpret_cast<uint4*>(ol + o)     = *reinterpret_cast<const uint4*>(lb);
            *reinterpret_cast<uint4*>(ol + o + 8) = *reinterpret_cast<const uint4*>(lb + 8);
        }
    }
}

// ---------------------------------------------------------------------------
// Prep 3: Wo[d][j] (f32 1024x1024) -> WoT[j][d] bf16 hi.
// ---------------------------------------------------------------------------
__global__ __launch_bounds__(256) void split_wo(
    const float* __restrict__ Wo, unsigned short* __restrict__ WoT)
{
    const int dt = blockIdx.x, jt = blockIdx.y;
    const int tid = threadIdx.x;
    __shared__ float lds[64][65];

    {
        int rr = tid >> 2, c4 = (tid & 3) * 16;
        const float* src = Wo + (size_t)(dt * 64 + rr) * DMODEL + jt * 64 + c4;
        #pragma unroll
        for (int i = 0; i < 4; ++i) {
            float4 v = *reinterpret_cast<const float4*>(src + i * 4);
            lds[rr][c4 + i * 4 + 0] = v.x;
            lds[rr][c4 + i * 4 + 1] = v.y;
            lds[rr][c4 + i * 4 + 2] = v.z;
            lds[rr][c4 + i * 4 + 3] = v.w;
        }
    }
    __syncthreads();
    {
        int jj = tid >> 2, d4 = (tid & 3) * 16;
        unsigned short hb[16];
        #pragma unroll
        for (int i = 0; i < 16; ++i) hb[i] = f2bf(lds[d4 + i][jj]);
        size_t o = (size_t)(jt * 64 + jj) * DMODEL + dt * 64 + d4;
        *reinterpret_cast<uint4*>(WoT + o)     = *reinterpret_cast<const uint4*>(hb);
        *reinterpret_cast<uint4*>(WoT + o + 8) = *reinterpret_cast<const uint4*>(hb + 8);
    }
}

// ---------------------------------------------------------------------------
// Kernel 1: per-head input projections, staging via global_load_lds.
// z=0,1 (Q,K): 3-term split-bf16 MFMA -> hi/lo bf16 head-major [h][n][k].
// z=2   (V) : 1-term MFMA -> bf16 TRANSPOSED per head: Vt[h][dv][token].
// ---------------------------------------------------------------------------
__global__ __launch_bounds__(256) void proj_kernel(
    const unsigned short* __restrict__ Ah0, const unsigned short* __restrict__ Ah1, const unsigned short* __restrict__ Ah2,
    const unsigned short* __restrict__ Al0, const unsigned short* __restrict__ Al1,
    const unsigned short* __restrict__ Wth0, const unsigned short* __restrict__ Wth1, const unsigned short* __restrict__ Wth2,
    const unsigned short* __restrict__ Wtl0, const unsigned short* __restrict__ Wtl1,
    const float* __restrict__ bq_, const float* __restrict__ bk_, const float* __restrict__ bv_,
    unsigned short* __restrict__ Qhh, unsigned short* __restrict__ Qhl,
    unsigned short* __restrict__ Khh, unsigned short* __restrict__ Khl,
    unsigned short* __restrict__ Vt)
{
    const int z = blockIdx.z;
    const unsigned short* Ah = (z == 0) ? Ah0 : (z == 1) ? Ah1 : Ah2;
    const unsigned short* Al = (z == 0) ? Al0 : Al1;
    const unsigned short* Bh = (z == 0) ? Wth0 : (z == 1) ? Wth1 : Wth2;
    const unsigned short* Bl = (z == 0) ? Wtl0 : Wtl1;
    const float* bias = (z == 0) ? bq_ : (z == 1) ? bk_ : bv_;

    __shared__ alignas(16) unsigned char sAh[16384];   // [128 rows][64 bf16] swizzled, hi
    __shared__ alignas(16) unsigned char sAl[16384];   // lo
    __shared__ alignas(16) unsigned char sBh[16384];   // [128 j][64 d] swizzled, hi
    __shared__ alignas(16) unsigned char sBl[16384];   // lo

    const int tid = threadIdx.x;
    const int lane = tid & 63;
    const int w = tid >> 6;               // 0..3
    const int wm = w >> 1, wn = w & 1;    // 2x2 wave grid
    const int g = lane >> 4, li = lane & 15;

    const int row0 = blockIdx.x * 128;    // token rows
    const int col0 = blockIdx.y * 128;    // output cols (h*64+k)

    f32x4 acc[4][4];
    #pragma unroll
    for (int m = 0; m < 4; ++m)
        #pragma unroll
        for (int n = 0; n < 4; ++n) acc[m][n] = f32x4{0.f, 0.f, 0.f, 0.f};

    for (int kt = 0; kt < DMODEL; kt += 64) {
        __syncthreads();
        #pragma unroll
        for (int p = 0; p < 4; ++p) {
            int chunk = p * 256 + tid;           // 16B chunk id, 0..1023
            int r = chunk >> 3, cc = chunk & 7;  // row, col-chunk
            int cs = (cc * 8) ^ ((r & 7) << 3);  // pre-swizzled short offset
            int ldso = (p * 256 + w * 64) * 16;  // wave-uniform LDS base
            gload16(Ah + (size_t)(row0 + r) * DMODEL + kt + cs, sAh + ldso);
            gload16(Bh + (size_t)(col0 + r) * DMODEL + kt + cs, sBh + ldso);
            if (z < 2) {
                gload16(Al + (size_t)(row0 + r) * DMODEL + kt + cs, sAl + ldso);
                gload16(Bl + (size_t)(col0 + r) * DMODEL + kt + cs, sBl + ldso);
            }
        }
        __syncthreads();

        if (z < 2) {
            #pragma unroll
            for (int kk = 0; kk < 2; ++kk) {
                bfrag afh[4], afl[4], bfh[4], bfl[4];
                #pragma unroll
                for (int m = 0; m < 4; ++m) {
                    afh[m] = *reinterpret_cast<const bfrag*>(sAh + swz(wm * 64 + m * 16 + li, kk * 64 + g * 16));
                    afl[m] = *reinterpret_cast<const bfrag*>(sAl + swz(wm * 64 + m * 16 + li, kk * 64 + g * 16));
                }
                #pragma unroll
                for (int n = 0; n < 4; ++n) {
                    bfh[n] = *reinterpret_cast<const bfrag*>(sBh + swz(wn * 64 + n * 16 + li, kk * 64 + g * 16));
                    bfl[n] = *reinterpret_cast<const bfrag*>(sBl + swz(wn * 64 + n * 16 + li, kk * 64 + g * 16));
                }
                #pragma unroll
                for (int m = 0; m < 4; ++m)
                    #pragma unroll
                    for (int n = 0; n < 4; ++n) {
                        acc[m][n] = __builtin_amdgcn_mfma_f32_16x16x32_bf16(afh[m], bfh[n], acc[m][n], 0, 0, 0);
                        acc[m][n] = __builtin_amdgcn_mfma_f32_16x16x32_bf16(afl[m], bfh[n], acc[m][n], 0, 0, 0);
                        acc[m][n] = __builtin_amdgcn_mfma_f32_16x16x32_bf16(afh[m], bfl[n], acc[m][n], 0, 0, 0);
                    }
            }
        } else {
            #pragma unroll
            for (int kk = 0; kk < 2; ++kk) {
                bfrag afh[4], bfh[4];
                #pragma unroll
                for (int m = 0; m < 4; ++m)
                    afh[m] = *reinterpret_cast<const bfrag*>(sAh + swz(wm * 64 + m * 16 + li, kk * 64 + g * 16));
                #pragma unroll
                for (int n = 0; n < 4; ++n)
                    bfh[n] = *reinterpret_cast<const bfrag*>(sBh + swz(wn * 64 + n * 16 + li, kk * 64 + g * 16));
                #pragma unroll
                for (int m = 0; m < 4; ++m)
                    #pragma unroll
                    for (int n = 0; n < 4; ++n)
                        acc[m][n] = __builtin_amdgcn_mfma_f32_16x16x32_bf16(afh[m], bfh[n], acc[m][n], 0, 0, 0);
            }
        }
    }

    // epilogue: +bias; Q,K -> hi/lo bf16 head-major; V -> bf16 transposed
    #pragma unroll
    for (int m = 0; m < 4; ++m) {
        #pragma unroll
        for (int n = 0; n < 4; ++n) {
            int colg = col0 + wn * 64 + n * 16 + li;
            float bb = bias[colg];
            int hh = colg >> 6, k = colg & 63;
            int rowb = row0 + wm * 64 + m * 16 + g * 4;
            if (z == 2) {
                unsigned short vb4[4];
                #pragma unroll
                for (int r = 0; r < 4; ++r) vb4[r] = f2bf(acc[m][n][r] + bb);
                *reinterpret_cast<uint2*>(Vt + ((size_t)hh * DK + k) * N_TOK + rowb) =
                    *reinterpret_cast<const uint2*>(vb4);
            } else {
                #pragma unroll
                for (int r = 0; r < 4; ++r) {
                    size_t o = ((size_t)hh * N_TOK + rowb + r) * DK + k;
                    float val = acc[m][n][r] + bb;
                    unsigned short hb = f2bf(val);
                    unsigned short lb = f2bf(val - bf2f(hb));
                    if (z == 0) { Qhh[o] = hb; Qhl[o] = lb; }
                    else        { Khh[o] = hb; Khl[o] = lb; }
                }
            }
        }
    }
}

// ---------------------------------------------------------------------------
// Kernel 2: flash attention, 32x32 MFMA, swapped operands both steps.
// Wave owns 32 q-rows (q = lane&31). S^T = K Q^T -> lane holds 16 keys of its
// q-row per 32-key block (other 16 in lane^32). Softmax fully in-lane +
// 1 shfl_xor(32). P -> bf16 via cvt_pk, PV B-frags built with shfl_xor(32)
// word exchange (no P LDS). O^T = V^T P keeps q = lane&31 in the accumulator.
// K/V double-buffered in LDS, raw barriers + counted vmcnt, setprio on MFMA.
// ---------------------------------------------------------------------------
__global__ __launch_bounds__(256) void attn_kernel(
    const unsigned short* __restrict__ Qhh, const unsigned short* __restrict__ Qhl,
    const unsigned short* __restrict__ Khh, const unsigned short* __restrict__ Khl,
    const unsigned short* __restrict__ Vt,
    float* __restrict__ Opart, float* __restrict__ mlbuf)
{
    __shared__ alignas(16) unsigned char sKh[2][8192];   // [64 key][64 k] swizzled, hi
    __shared__ alignas(16) unsigned char sKl[2][8192];   // lo
    __shared__ alignas(16) unsigned char sV [2][8192];   // [64 dv][64 key] swizzled

    // XCD swizzle: 64-block contiguous chunks per XCD
    const int bid = blockIdx.x;                  // 0..511
    const int orig = (bid & 7) * 64 + (bid >> 3);
    const int h    = orig >> 5;
    const int half = (orig >> 4) & 1;
    const int qt   = orig & 15;

    const int tid  = threadIdx.x;
    const int lane = tid & 63;
    const int w    = tid >> 6;            // 0..3
    const int q31  = lane & 31;
    const int hi   = lane >> 5;
    const int qrow0 = qt * 128 + w * 32;

    const unsigned short* QbH = Qhh + (size_t)h * N_TOK * DK;
    const unsigned short* QbL = Qhl + (size_t)h * N_TOK * DK;
    const unsigned short* KbH = Khh + (size_t)h * N_TOK * DK;
    const unsigned short* KbL = Khl + (size_t)h * N_TOK * DK;
    const unsigned short* Vtb = Vt  + (size_t)h * DK * N_TOK;

    // Q B-fragments (hi/lo): lane holds Q[q=q31][dk = d*16 + hi*8 + j]
    bfrag bqh[4], bql[4];
    #pragma unroll
    for (int d = 0; d < 4; ++d) {
        size_t o = (size_t)(qrow0 + q31) * DK + d * 16 + hi * 8;
        bqh[d] = *reinterpret_cast<const bfrag*>(QbH + o);
        bql[d] = *reinterpret_cast<const bfrag*>(QbL + o);
    }

    f32x16 acc0 = {}, acc1 = {};          // O^T dv-blocks 0/1, col q = q31
    float mrun = -3.0e38f, lrun = 0.f;

    const int tbase = half * (N_TOK / 2);

#define STAGE(B, T) do {                                                     \
    _Pragma("unroll")                                                        \
    for (int p_ = 0; p_ < 2; ++p_) {                                         \
        int chunk_ = p_ * 256 + w * 64 + lane;                               \
        int r_ = chunk_ >> 3;                                                \
        int cs_ = ((chunk_ & 7) * 8) ^ ((r_ & 7) << 3);                      \
        int ldso_ = (p_ * 256 + w * 64) * 16;                                \
        gload16(KbH + (size_t)((T) + r_) * DK + cs_, sKh[B] + ldso_);        \
        gload16(KbL + (size_t)((T) + r_) * DK + cs_, sKl[B] + ldso_);        \
        gload16(Vtb + (size_t)r_ * N_TOK + (T) + cs_, sV[B] + ldso_);        \
    } } while (0)

#define MKFRAG(W, PF) do {                                                   \
    _Pragma("unroll")                                                        \
    for (int kk_ = 0; kk_ < 2; ++kk_) {                                      \
        unsigned b0_ = W[4 * kk_ + 0], b1_ = W[4 * kk_ + 1];                 \
        unsigned a0_ = W[4 * kk_ + 2], a1_ = W[4 * kk_ + 3];                 \
        unsigned sb0_ = (unsigned)__shfl_xor((int)b0_, 32);                  \
        unsigned sa0_ = (unsigned)__shfl_xor((int)a0_, 32);                  \
        unsigned sb1_ = (unsigned)__shfl_xor((int)b1_, 32);                  \
        unsigned sa1_ = (unsigned)__shfl_xor((int)a1_, 32);                  \
        u32x4 t_ = { hi ? sa0_ : b0_, hi ? sa1_ : b1_,                       \
                     hi ? a0_ : sb0_, hi ? a1_ : sb1_ };                     \
        PF[kk_] = __builtin_bit_cast(bfrag, t_);                             \
    } } while (0)

    STAGE(0, tbase);

    for (int tt = 0; tt < 16; ++tt) {
        const int cur = tt & 1;
        if (tt < 15) {
            STAGE(cur ^ 1, tbase + (tt + 1) * 64);
            asm volatile("s_waitcnt vmcnt(6)" ::: "memory");
        } else {
            asm volatile("s_waitcnt vmcnt(0)" ::: "memory");
        }
        __builtin_amdgcn_s_barrier();
        asm volatile("" ::: "memory");

        // --- S^T = K Q^T, 3-term split-bf16, key-blocks kb=0,1 ---
        f32x16 s0 = {}, s1 = {};
        __builtin_amdgcn_s_setprio(1);
        #pragma unroll
        for (int d = 0; d < 4; ++d) {
            const int bo = d * 32 + hi * 16;
            bfrag kh0 = *reinterpret_cast<const bfrag*>(sKh[cur] + swz(q31,      bo));
            bfrag kl0 = *reinterpret_cast<const bfrag*>(sKl[cur] + swz(q31,      bo));
            bfrag kh1 = *reinterpret_cast<const bfrag*>(sKh[cur] + swz(32 + q31, bo));
            bfrag kl1 = *reinterpret_cast<const bfrag*>(sKl[cur] + swz(32 + q31, bo));
            s0 = __builtin_amdgcn_mfma_f32_32x32x16_bf16(kh0, bqh[d], s0, 0, 0, 0);
            s1 = __builtin_amdgcn_mfma_f32_32x32x16_bf16(kh1, bqh[d], s1, 0, 0, 0);
            s0 = __builtin_amdgcn_mfma_f32_32x32x16_bf16(kl0, bqh[d], s0, 0, 0, 0);
            s1 = __builtin_amdgcn_mfma_f32_32x32x16_bf16(kl1, bqh[d], s1, 0, 0, 0);
            s0 = __builtin_amdgcn_mfma_f32_32x32x16_bf16(kh0, bql[d], s0, 0, 0, 0);
            s1 = __builtin_amdgcn_mfma_f32_32x32x16_bf16(kh1, bql[d], s1, 0, 0, 0);
        }
        __builtin_amdgcn_s_setprio(0);

        // --- online softmax: lane owns q-row q31 (16+16 keys; rest in lane^32)
        float t0 = fmaxf(fmaxf(s0[0],  s0[1]),  fmaxf(s0[2],  s0[3]));
        float t1 = fmaxf(fmaxf(s0[4],  s0[5]),  fmaxf(s0[6],  s0[7]));
        float t2 = fmaxf(fmaxf(s0[8],  s0[9]),  fmaxf(s0[10], s0[11]));
        float t3 = fmaxf(fmaxf(s0[12], s0[13]), fmaxf(s0[14], s0[15]));
        float u0 = fmaxf(fmaxf(s1[0],  s1[1]),  fmaxf(s1[2],  s1[3]));
        float u1 = fmaxf(fmaxf(s1[4],  s1[5]),  fmaxf(s1[6],  s1[7]));
        float u2 = fmaxf(fmaxf(s1[8],  s1[9]),  fmaxf(s1[10], s1[11]));
        float u3 = fmaxf(fmaxf(s1[12], s1[13]), fmaxf(s1[14], s1[15]));
        float tm = fmaxf(fmaxf(fmaxf(t0, t1), fmaxf(t2, t3)),
                         fmaxf(fmaxf(u0, u1), fmaxf(u2, u3)));
        tm = fmaxf(tm, __shfl_xor(tm, 32));
        float nm = fmaxf(mrun, tm);
        float sc = __expf(mrun - nm);
        mrun = nm;
        lrun *= sc;
        #pragma unroll
        for (int r = 0; r < 16; ++r) { acc0[r] *= sc; acc1[r] *= sc; }

        float p0[16], p1[16];
        #pragma unroll
        for (int r = 0; r < 16; ++r) p0[r] = __expf(s0[r] - nm);
        #pragma unroll
        for (int r = 0; r < 16; ++r) p1[r] = __expf(s1[r] - nm);
        float ps = ((p0[0] + p0[1]) + (p0[2] + p0[3])) + ((p0[4] + p0[5]) + (p0[6] + p0[7]))
                 + ((p0[8] + p0[9]) + (p0[10] + p0[11])) + ((p0[12] + p0[13]) + (p0[14] + p0[15]))
                 + ((p1[0] + p1[1]) + (p1[2] + p1[3])) + ((p1[4] + p1[5]) + (p1[6] + p1[7]))
                 + ((p1[8] + p1[9]) + (p1[10] + p1[11])) + ((p1[12] + p1[13]) + (p1[14] + p1[15]));
        ps += __shfl_xor(ps, 32);
        lrun += ps;

        // --- P -> bf16 words, exchange halves -> PV B-fragments (in-register)
        unsigned w0[8], w1[8];
        #pragma unroll
        for (int j = 0; j < 8; ++j) w0[j] = cvtpk(p0[2 * j], p0[2 * j + 1]);
        #pragma unroll
        for (int j = 0; j < 8; ++j) w1[j] = cvtpk(p1[2 * j], p1[2 * j + 1]);
        bfrag pf0[2], pf1[2];
        MKFRAG(w0, pf0);
        MKFRAG(w1, pf1);

        // --- O^T += V^T P (dv-blocks 0/1, key-slices ks=0..3) ---
        __builtin_amdgcn_s_setprio(1);
        #pragma unroll
        for (int ks = 0; ks < 4; ++ks) {
            bfrag pb = (ks < 2) ? pf0[ks & 1] : pf1[ks & 1];
            const int bo = ks * 32 + hi * 16;
            bfrag va0 = *reinterpret_cast<const bfrag*>(sV[cur] + swz(q31,      bo));
            bfrag va1 = *reinterpret_cast<const bfrag*>(sV[cur] + swz(32 + q31, bo));
            acc0 = __builtin_amdgcn_mfma_f32_32x32x16_bf16(va0, pb, acc0, 0, 0, 0);
            acc1 = __builtin_amdgcn_mfma_f32_32x32x16_bf16(va1, pb, acc1, 0, 0, 0);
        }
        __builtin_amdgcn_s_setprio(0);
        asm volatile("" ::: "memory");
        __builtin_amdgcn_s_barrier();
    }
#undef STAGE
#undef MKFRAG

    // epilogue: unnormalized partial O (f32) + per-row (m,l)
    const size_t pbase = (size_t)half * NH * N_TOK;
    const size_t idxp = pbase + (size_t)h * N_TOK + qrow0 + q31;
    float* op = Opart + idxp * 64;
    #pragma unroll
    for (int m = 0; m < 4; ++m) {
        float4 v0 = make_float4(acc0[4 * m], acc0[4 * m + 1], acc0[4 * m + 2], acc0[4 * m + 3]);
        float4 v1 = make_float4(acc1[4 * m], acc1[4 * m + 1], acc1[4 * m + 2], acc1[4 * m + 3]);
        *reinterpret_cast<float4*>(op + 8 * m + 4 * hi)      = v0;   // dv = e+8m+4hi
        *reinterpret_cast<float4*>(op + 32 + 8 * m + 4 * hi) = v1;
    }
    if (lane < 32)
        *reinterpret_cast<float2*>(mlbuf + idxp * 2) = make_float2(mrun, lrun);
}

// ---------------------------------------------------------------------------
// Kernel 2b: merge the two KV-half partials -> Hc bf16 [n][h*64+dv].
// ---------------------------------------------------------------------------
__global__ __launch_bounds__(256) void combine_kernel(
    const float* __restrict__ Opart, const float* __restrict__ mlbuf,
    unsigned short* __restrict__ Hc)
{
    const int tid = threadIdx.x;
    const int sub = tid & 3;
    const int idx = blockIdx.x * 64 + (tid >> 2);   // h*2048+row
    const int h = idx >> 11, row = idx & 2047;
    const int HALFSZ = NH * N_TOK;

    float2 a = *reinterpret_cast<const float2*>(mlbuf + (size_t)idx * 2);
    float2 b = *reinterpret_cast<const float2*>(mlbuf + ((size_t)HALFSZ + idx) * 2);
    float M = fmaxf(a.x, b.x);
    float c1 = __expf(a.x - M), c2 = __expf(b.x - M);
    float scale = 0.125f / (a.y * c1 + b.y * c2);
    float s1 = c1 * scale, s2 = c2 * scale;

    const float* O1 = Opart + (size_t)idx * 64 + sub * 16;
    const float* O2 = Opart + ((size_t)HALFSZ + idx) * 64 + sub * 16;
    unsigned short hb[16];
    #pragma unroll
    for (int i = 0; i < 4; ++i) {
        float4 x = *reinterpret_cast<const float4*>(O1 + i * 4);
        float4 y = *reinterpret_cast<const float4*>(O2 + i * 4);
        hb[i * 4 + 0] = f2bf(x.x * s1 + y.x * s2);
        hb[i * 4 + 1] = f2bf(x.y * s1 + y.y * s2);
        hb[i * 4 + 2] = f2bf(x.z * s1 + y.z * s2);
        hb[i * 4 + 3] = f2bf(x.w * s1 + y.w * s2);
    }
    size_t o = (size_t)row * DMODEL + h * 64 + sub * 16;
    *reinterpret_cast<uint4*>(Hc + o)     = *reinterpret_cast<const uint4*>(hb);
    *reinterpret_cast<uint4*>(Hc + o + 8) = *reinterpret_cast<const uint4*>(hb + 8);
}

// ---------------------------------------------------------------------------
// Kernel 3: output projection, all-bf16 via pre-transposed WoT.
// Tile 64x128 (grid 32x8 = 256 blocks), BK=64, 4 waves (2x2), gload staging.
// ---------------------------------------------------------------------------
__global__ __launch_bounds__(256) void oproj_kernel(
    const unsigned short* __restrict__ Hc,
    const unsigned short* __restrict__ WoT,
    const float* __restrict__ bo,
    float* __restrict__ out)
{
    __shared__ alignas(16) unsigned char sA[8192];    // [64][64] bf16 swizzled
    __shared__ alignas(16) unsigned char sB[16384];   // [128 j][64 d] swizzled

    const int tid = threadIdx.x;
    const int lane = tid & 63;
    const int w = tid >> 6;
    const int wm = w >> 1, wn = w & 1;
    const int g = lane >> 4, li = lane & 15;
    const int row0 = blockIdx.x * 64;
    const int col0 = blockIdx.y * 128;

    f32x4 acc[2][4];
    #pragma unroll
    for (int m = 0; m < 2; ++m)
        #pragma unroll
        for (int n = 0; n < 4; ++n) acc[m][n] = f32x4{0.f, 0.f, 0.f, 0.f};

    for (int kt = 0; kt < DMODEL; kt += 64) {
        __syncthreads();
        #pragma unroll
        for (int p = 0; p < 2; ++p) {
            int chunk = p * 256 + tid;
            int r = chunk >> 3, cc = chunk & 7;
            int cs = (cc * 8) ^ ((r & 7) << 3);
            int ldso = (p * 256 + w * 64) * 16;
            gload16(Hc + (size_t)(row0 + r) * DMODEL + kt + cs, sA + ldso);
        }
        #pragma unroll
        for (int p = 0; p < 4; ++p) {
            int chunk = p * 256 + tid;
            int r = chunk >> 3, cc = chunk & 7;
            int cs = (cc * 8) ^ ((r & 7) << 3);
            int ldso = (p * 256 + w * 64) * 16;
            gload16(WoT + (size_t)(col0 + r) * DMODEL + kt + cs, sB + ldso);
        }
        __syncthreads();

        #pragma unroll
        for (int kk = 0; kk < 2; ++kk) {
            bfrag af[2], bf_[4];
            #pragma unroll
            for (int m = 0; m < 2; ++m)
                af[m] = *reinterpret_cast<const bfrag*>(sA + swz(wm * 32 + m * 16 + li, kk * 64 + g * 16));
            #pragma unroll
            for (int n = 0; n < 4; ++n)
                bf_[n] = *reinterpret_cast<const bfrag*>(sB + swz(wn * 64 + n * 16 + li, kk * 64 + g * 16));
            #pragma unroll
            for (int m = 0; m < 2; ++m)
                #pragma unroll
                for (int n = 0; n < 4; ++n)
                    acc[m][n] = __builtin_amdgcn_mfma_f32_16x16x32_bf16(af[m], bf_[n], acc[m][n], 0, 0, 0);
        }
    }

    #pragma unroll
    for (int m = 0; m < 2; ++m) {
        #pragma unroll
        for (int n = 0; n < 4; ++n) {
            int colg = col0 + wn * 64 + n * 16 + li;
            float bb = bo[colg];
            #pragma unroll
            for (int r = 0; r < 4; ++r) {
                int rowg = row0 + wm * 32 + m * 16 + g * 4 + r;
                out[(size_t)rowg * DMODEL + colg] = acc[m][n][r] + bb;
            }
        }
    }
}

extern "C" void kernel_launch(void* const* d_in, const int* in_sizes, int n_in,
                              void* d_out, int out_size, void* d_ws, size_t ws_size,
                              hipStream_t stream) {
    (void)in_sizes; (void)n_in; (void)out_size; (void)ws_size;
    const float* Q  = (const float*)d_in[0];
    const float* K  = (const float*)d_in[1];
    const float* V  = (const float*)d_in[2];
    // d_in[3] = mask (unused by reference forward)
    const float* Wq = (const float*)d_in[4];
    const float* bq = (const float*)d_in[5];
    const float* Wk = (const float*)d_in[6];
    const float* bk = (const float*)d_in[7];
    const float* Wv = (const float*)d_in[8];
    const float* bv = (const float*)d_in[9];
    const float* Wo = (const float*)d_in[10];
    const float* bo = (const float*)d_in[11];
    float* out = (float*)d_out;

    const size_t ASZ = (size_t)N_TOK * DMODEL;   // 2M elems
    const size_t WSZ = (size_t)NH * DK * DMODEL; // 1M elems
    const size_t HSZ = (size_t)NH * N_TOK * DK;  // 2M elems
    unsigned short* p = (unsigned short*)d_ws;
    unsigned short* Ah0 = p; p += ASZ;
    unsigned short* Ah1 = p; p += ASZ;
    unsigned short* Ah2 = p; p += ASZ;
    unsigned short* Al0 = p; p += ASZ;
    unsigned short* Al1 = p; p += ASZ;
    unsigned short* Wth0 = p; p += WSZ;
    unsigned short* Wth1 = p; p += WSZ;
    unsigned short* Wth2 = p; p += WSZ;
    unsigned short* Wtl0 = p; p += WSZ;
    unsigned short* Wtl1 = p; p += WSZ;
    unsigned short* Qhh = p; p += HSZ;
    unsigned short* Qhl = p; p += HSZ;
    unsigned short* Khh = p; p += HSZ;
    unsigned short* Khl = p; p += HSZ;
    unsigned short* Vt  = p; p += HSZ;
    unsigned short* Hc  = p; p += HSZ;
    unsigned short* WoT = p; p += ASZ / 2;       // 1M elems (1024x1024 bf16)

    // attn partials alias the Ah/Al prep region (dead after proj_kernel):
    float* Opart = (float*)d_ws;
    float* mlbuf = Opart + (size_t)2 * NH * N_TOK * 64;

    split_act<<<dim3(1024, 3), 256, 0, stream>>>(Q, K, V, Ah0, Ah1, Ah2, Al0, Al1);
    split_w<<<dim3(16, 16, 3), 256, 0, stream>>>(Wq, Wk, Wv, Wth0, Wth1, Wth2, Wtl0, Wtl1);
    split_wo<<<dim3(16, 16), 256, 0, stream>>>(Wo, WoT);
    proj_kernel<<<dim3(16, 8, 3), 256, 0, stream>>>(
        Ah0, Ah1, Ah2, Al0, Al1, Wth0, Wth1, Wth2, Wtl0, Wtl1,
        bq, bk, bv, Qhh, Qhl, Khh, Khl, Vt);
    attn_kernel<<<dim3(512), 256, 0, stream>>>(Qhh, Qhl, Khh, Khl, Vt, Opart, mlbuf);
    combine_kernel<<<dim3(512), 256, 0, stream>>>(Opart, mlbuf, Hc);
    oproj_kernel<<<dim3(32, 8), 256, 0, stream>>>(Hc, WoT, bo, out);
}